// Round 5
// baseline (3051.876 us; speedup 1.0000x reference)
//
#include <hip/hip_runtime.h>
#include <math.h>

#define N_ROWS 65536
#define DIM    256
#define NCODE  4096

#define BM 64
#define BC 64
#define DK 64
#define LDP 68      // padded LDS row stride (floats); 272B = 17*16B, 16B-aligned
#define MARGIN 2e-4f

// ---------------- codebook normalize (f64 norm): cbn32, c2 (fp32 path), c2d/nd (f64 path)
__global__ void cb_norm_kernel(const float* __restrict__ cb,
                               float* __restrict__ cbn,
                               float* __restrict__ c2,
                               double* __restrict__ c2d,
                               double* __restrict__ nd) {
    int k = blockIdx.x;
    int t = threadIdx.x;
    float v = cb[k * DIM + t];
    double dv = (double)v;
    double ss = dv * dv;
    __shared__ double red[4], red2[4], red3[4];
    #pragma unroll
    for (int off = 32; off > 0; off >>= 1) ss += __shfl_down(ss, off);
    if ((t & 63) == 0) red[t >> 6] = ss;
    __syncthreads();
    double S = red[0] + red[1] + red[2] + red[3];
    double nrm = fmax(sqrt(S), 1e-12);
    double inv = 1.0 / nrm;
    double cq = dv * inv;          // f64 normalized value
    float cf = (float)cq;          // fp32 normalized value (correctly rounded)
    cbn[k * DIM + t] = cf;
    double s2 = (double)cf * (double)cf;  // for fp32-path c2 (accurate)
    double s3 = cq * cq;                  // for f64-path c2
    #pragma unroll
    for (int off = 32; off > 0; off >>= 1) {
        s2 += __shfl_down(s2, off);
        s3 += __shfl_down(s3, off);
    }
    if ((t & 63) == 0) { red2[t >> 6] = s2; red3[t >> 6] = s3; }
    __syncthreads();
    if (t == 0) {
        c2[k]  = (float)(red2[0] + red2[1] + red2[2] + red2[3]);
        c2d[k] = red3[0] + red3[1] + red3[2] + red3[3];
        nd[k]  = nrm;
    }
}

// ---------------- per-row x norms in f64; also zero the fixup counter
__global__ void x_norm_kernel(const float* __restrict__ x,
                              float* __restrict__ nx,
                              float* __restrict__ scx,
                              int* __restrict__ counter) {
    if (blockIdx.x == 0 && threadIdx.x == 0) counter[0] = 0;
    int w = threadIdx.x >> 6;
    int lane = threadIdx.x & 63;
    int row = blockIdx.x * 4 + w;
    float4 v = ((const float4*)(x + (size_t)row * DIM))[lane];
    double ss = (double)v.x * v.x + (double)v.y * v.y
              + (double)v.z * v.z + (double)v.w * v.w;
    #pragma unroll
    for (int off = 32; off > 0; off >>= 1) ss += __shfl_down(ss, off);
    if (lane == 0) {
        double n = fmax(sqrt(ss), 1e-12);
        nx[row]  = (float)n;
        scx[row] = (float)(2.0 / n);
    }
}

// ---------------- main: fp32 dot GEMM + streaming exact top-2 argmin epilogue
__launch_bounds__(256, 4)
__global__ void argmin_kernel(const float* __restrict__ x,
                              const float* __restrict__ cbn,
                              const float* __restrict__ c2,
                              const float* __restrict__ scx,
                              int* __restrict__ idx_out,
                              int* __restrict__ counter,
                              int* __restrict__ rowlist) {
    __shared__ float Xs[DK][LDP];
    __shared__ float Cs[DK][LDP];

    int tid = threadIdx.x;
    int tx = tid & 15;   // code group
    int ty = tid >> 4;   // row group
    int rowBase = blockIdx.x * BM;

    float scr[4];
    #pragma unroll
    for (int i = 0; i < 4; i++) scr[i] = scx[rowBase + ty * 4 + i];

    // per-thread exact best-2 over this thread's code stream
    float t_s1[4], t_s2[4];
    int   t_i1[4];
    #pragma unroll
    for (int i = 0; i < 4; i++) { t_s1[i] = 3.4e38f; t_s2[i] = 3.4e38f; t_i1[i] = 0x7fffffff; }

    for (int cc = 0; cc < NCODE / BC; cc++) {
        float acc[4][4];
        #pragma unroll
        for (int i = 0; i < 4; i++)
            #pragma unroll
            for (int j = 0; j < 4; j++) acc[i][j] = 0.0f;

        for (int dk = 0; dk < DIM / DK; dk++) {
            #pragma unroll
            for (int it = 0; it < 4; it++) {
                int f  = tid + 256 * it;   // float4 id, 1024 total
                int r  = f >> 4;           // 16 float4 per row
                int d4 = f & 15;
                float4 v = *(const float4*)(x + (size_t)(rowBase + r) * DIM + dk * DK + d4 * 4);
                Xs[d4 * 4 + 0][r] = v.x;
                Xs[d4 * 4 + 1][r] = v.y;
                Xs[d4 * 4 + 2][r] = v.z;
                Xs[d4 * 4 + 3][r] = v.w;
                float4 w = *(const float4*)(cbn + (size_t)(cc * BC + r) * DIM + dk * DK + d4 * 4);
                Cs[d4 * 4 + 0][r] = w.x;
                Cs[d4 * 4 + 1][r] = w.y;
                Cs[d4 * 4 + 2][r] = w.z;
                Cs[d4 * 4 + 3][r] = w.w;
            }
            __syncthreads();

            #pragma unroll 4
            for (int d = 0; d < DK; d++) {
                float4 a = *(const float4*)&Xs[d][ty * 4];
                float4 b = *(const float4*)&Cs[d][tx * 4];
                float av[4] = {a.x, a.y, a.z, a.w};
                float bv[4] = {b.x, b.y, b.z, b.w};
                #pragma unroll
                for (int i = 0; i < 4; i++)
                    #pragma unroll
                    for (int j = 0; j < 4; j++)
                        acc[i][j] += av[i] * bv[j];
            }
            __syncthreads();
        }

        // epilogue: update per-thread best-2 (codes ascend -> strict < keeps first)
        #pragma unroll
        for (int i = 0; i < 4; i++) {
            #pragma unroll
            for (int j = 0; j < 4; j++) {
                int   ci = cc * BC + tx * 4 + j;
                float s  = c2[ci] - scr[i] * acc[i][j];
                if (s < t_s1[i]) { t_s2[i] = t_s1[i]; t_s1[i] = s; t_i1[i] = ci; }
                else if (s < t_s2[i]) t_s2[i] = s;
            }
        }
    }

    // exact global top-2 merge across the 16 lanes of this row group
    #pragma unroll
    for (int i = 0; i < 4; i++) {
        float a1 = t_s1[i]; int ai = t_i1[i]; float a2 = t_s2[i];
        #pragma unroll
        for (int m = 1; m < 16; m <<= 1) {
            float b1 = __shfl_xor(a1, m);
            int   bi = __shfl_xor(ai, m);
            float b2 = __shfl_xor(a2, m);
            if (b1 < a1 || (b1 == a1 && bi < ai)) { a2 = fminf(a1, b2); a1 = b1; ai = bi; }
            else                                  { a2 = fminf(b1, a2); }
        }
        if (tx == 0) {
            int row = rowBase + ty * 4 + i;
            idx_out[row] = ai;
            if (a2 - a1 < MARGIN) {           // near-tie: queue exact f64 rescore
                int slot = atomicAdd(counter, 1);
                rowlist[slot] = row;
            }
        }
    }
}

// ---------------- f64 exact rescore for near-tie rows (full 4096-code scan)
__global__ void fixup_kernel(const float* __restrict__ x,
                             const float* __restrict__ cb,
                             const double* __restrict__ c2d,
                             const double* __restrict__ nd,
                             const int* __restrict__ counter,
                             const int* __restrict__ rowlist,
                             int* __restrict__ idxv) {
    __shared__ double xs[DIM];
    __shared__ double rn[4];
    __shared__ double rs[4];
    __shared__ int    ri[4];
    int t = threadIdx.x, lane = t & 63, w = t >> 6;
    int cnt = counter[0];
    for (int li = blockIdx.x; li < cnt; li += gridDim.x) {
        int row = rowlist[li];
        double xv = (double)x[(size_t)row * DIM + t];
        double ss = xv * xv;
        #pragma unroll
        for (int off = 32; off > 0; off >>= 1) ss += __shfl_down(ss, off);
        if (lane == 0) rn[w] = ss;
        xs[t] = xv;
        __syncthreads();
        double xnorm = fmax(sqrt(rn[0] + rn[1] + rn[2] + rn[3]), 1e-12);
        double isx = 2.0 / xnorm;
        double bs = 1e300; int bi = 0x7fffffff;
        for (int k0 = 0; k0 < NCODE / 256; k0++) {
            int k = k0 * 256 + t;
            const float4* cr = (const float4*)(cb + (size_t)k * DIM);
            double dot = 0.0;
            #pragma unroll 8
            for (int d4 = 0; d4 < DIM / 4; d4++) {
                float4 c = cr[d4];
                dot += (double)c.x * xs[d4 * 4 + 0] + (double)c.y * xs[d4 * 4 + 1]
                     + (double)c.z * xs[d4 * 4 + 2] + (double)c.w * xs[d4 * 4 + 3];
            }
            double s = c2d[k] - isx * dot / nd[k];
            if (s < bs || (s == bs && k < bi)) { bs = s; bi = k; }
        }
        #pragma unroll
        for (int m = 1; m < 64; m <<= 1) {
            double os = __shfl_xor(bs, m);
            int   oi = __shfl_xor(bi, m);
            if (os < bs || (os == bs && oi < bi)) { bs = os; bi = oi; }
        }
        if (lane == 0) { rs[w] = bs; ri[w] = bi; }
        __syncthreads();
        if (t == 0) {
            for (int ww = 1; ww < 4; ww++)
                if (rs[ww] < bs || (rs[ww] == bs && ri[ww] < bi)) { bs = rs[ww]; bi = ri[ww]; }
            idxv[row] = bi;
        }
        __syncthreads();
    }
}

// ---------------- gather + per-row loss partial
__global__ void gather_loss_kernel(const float* __restrict__ x,
                                   const float* __restrict__ cbn,
                                   const float* __restrict__ c2,
                                   const float* __restrict__ nx,
                                   const int* __restrict__ idxv,
                                   float* __restrict__ out_q,
                                   float* __restrict__ out_idxf,
                                   float* __restrict__ partials) {
    int row = blockIdx.x;
    int t = threadIdx.x;
    int iv = idxv[row];
    float q = cbn[(size_t)iv * DIM + t];
    float qn = fmaxf(sqrtf(c2[iv]), 1e-12f);
    q = q / qn;
    float xv = x[(size_t)row * DIM + t] / nx[row];
    out_q[(size_t)row * DIM + t] = q;
    float d = q - xv;
    float ss = d * d;
    __shared__ float red[4];
    #pragma unroll
    for (int off = 32; off > 0; off >>= 1) ss += __shfl_down(ss, off);
    if ((t & 63) == 0) red[t >> 6] = ss;
    __syncthreads();
    if (t == 0) {
        partials[row] = red[0] + red[1] + red[2] + red[3];
        out_idxf[row] = (float)iv;
    }
}

// ---------------- final deterministic loss reduction
__global__ void loss_reduce_kernel(const float* __restrict__ partials,
                                   float* __restrict__ out_loss) {
    int t = threadIdx.x;
    float s = 0.0f;
    for (int i = t; i < N_ROWS; i += 256) s += partials[i];
    __shared__ float red[4];
    #pragma unroll
    for (int off = 32; off > 0; off >>= 1) s += __shfl_down(s, off);
    if ((t & 63) == 0) red[t >> 6] = s;
    __syncthreads();
    if (t == 0) out_loss[0] = 1.25f * (red[0] + red[1] + red[2] + red[3]) / (float)(N_ROWS * DIM);
}

extern "C" void kernel_launch(void* const* d_in, const int* in_sizes, int n_in,
                              void* d_out, int out_size, void* d_ws, size_t ws_size,
                              hipStream_t stream) {
    const float* x  = (const float*)d_in[0];
    const float* cb = (const float*)d_in[1];
    float* out = (float*)d_out;

    double* c2d = (double*)d_ws;                      // 4096 doubles
    double* nd  = c2d + NCODE;                        // 4096 doubles
    float* cbn = (float*)(nd + NCODE);                // 4096*256
    float* c2  = cbn + (size_t)NCODE * DIM;           // 4096
    float* nx  = c2 + NCODE;                          // 65536
    float* scx = nx + N_ROWS;                         // 65536
    int*   idxv = (int*)(scx + N_ROWS);               // 65536
    float* partials = (float*)(idxv + N_ROWS);        // 65536
    int*   counter  = (int*)(partials + N_ROWS);      // 1 (+3 pad)
    int*   rowlist  = counter + 4;                    // 65536

    float* out_q    = out;
    float* out_loss = out + (size_t)N_ROWS * DIM;
    float* out_idxf = out_loss + 1;

    hipLaunchKernelGGL(cb_norm_kernel, dim3(NCODE), dim3(256), 0, stream, cb, cbn, c2, c2d, nd);
    hipLaunchKernelGGL(x_norm_kernel, dim3(N_ROWS / 4), dim3(256), 0, stream, x, nx, scx, counter);
    hipLaunchKernelGGL(argmin_kernel, dim3(N_ROWS / BM), dim3(256), 0, stream,
                       x, cbn, c2, scx, idxv, counter, rowlist);
    hipLaunchKernelGGL(fixup_kernel, dim3(128), dim3(256), 0, stream,
                       x, cb, c2d, nd, counter, rowlist, idxv);
    hipLaunchKernelGGL(gather_loss_kernel, dim3(N_ROWS), dim3(256), 0, stream,
                       x, cbn, c2, nx, idxv, out_q, out_idxf, partials);
    hipLaunchKernelGGL(loss_reduce_kernel, dim3(1), dim3(256), 0, stream,
                       partials, out_loss);
}

// Round 6
// 1599.855 us; speedup vs baseline: 1.9076x; 1.9076x over previous
//
#include <hip/hip_runtime.h>
#include <math.h>

#define N_ROWS 65536
#define DIM    256
#define NCODE  4096
#define MARGIN 2e-4f

typedef __attribute__((ext_vector_type(8))) short short8v;
typedef __attribute__((ext_vector_type(4))) float float4v;

__device__ inline unsigned short f2bf(float f) {
    unsigned u = __float_as_uint(f);
    unsigned r = (u + 0x7fffu + ((u >> 16) & 1u)) >> 16;
    return (unsigned short)r;
}
__device__ inline float bf2f(unsigned short h) {
    return __uint_as_float(((unsigned)h) << 16);
}

// ---------------- codebook normalize (f64 norm): cbn fp32, bf16 split (ch,cl), c2/c2d/nd
__global__ void cb_norm_kernel(const float* __restrict__ cb,
                               float* __restrict__ cbn,
                               unsigned short* __restrict__ ch,
                               unsigned short* __restrict__ cl,
                               float* __restrict__ c2,
                               double* __restrict__ c2d,
                               double* __restrict__ nd) {
    int k = blockIdx.x;
    int t = threadIdx.x;
    float v = cb[k * DIM + t];
    double dv = (double)v;
    double ss = dv * dv;
    __shared__ double red2[4], red3[4];
    __shared__ double redn[4];
    #pragma unroll
    for (int off = 32; off > 0; off >>= 1) ss += __shfl_down(ss, off);
    if ((t & 63) == 0) redn[t >> 6] = ss;
    __syncthreads();
    double S = redn[0] + redn[1] + redn[2] + redn[3];
    double nrm = fmax(sqrt(S), 1e-12);
    double inv = 1.0 / nrm;
    double cq = dv * inv;
    float cf = (float)cq;
    cbn[k * DIM + t] = cf;
    unsigned short hb = f2bf(cf);
    ch[k * DIM + t] = hb;
    cl[k * DIM + t] = f2bf(cf - bf2f(hb));
    double s2 = (double)cf * (double)cf;
    double s3 = cq * cq;
    #pragma unroll
    for (int off = 32; off > 0; off >>= 1) {
        s2 += __shfl_down(s2, off);
        s3 += __shfl_down(s3, off);
    }
    if ((t & 63) == 0) { red2[t >> 6] = s2; red3[t >> 6] = s3; }
    __syncthreads();
    if (t == 0) {
        c2[k]  = (float)(red2[0] + red2[1] + red2[2] + red2[3]);
        c2d[k] = red3[0] + red3[1] + red3[2] + red3[3];
        nd[k]  = nrm;
    }
}

// ---------------- per-row x norms in f64; also zero the fixup counter
__global__ void x_norm_kernel(const float* __restrict__ x,
                              float* __restrict__ nx,
                              float* __restrict__ scx,
                              int* __restrict__ counter) {
    if (blockIdx.x == 0 && threadIdx.x == 0) counter[0] = 0;
    int w = threadIdx.x >> 6;
    int lane = threadIdx.x & 63;
    int row = blockIdx.x * 4 + w;
    float4 v = ((const float4*)(x + (size_t)row * DIM))[lane];
    double ss = (double)v.x * v.x + (double)v.y * v.y
              + (double)v.z * v.z + (double)v.w * v.w;
    #pragma unroll
    for (int off = 32; off > 0; off >>= 1) ss += __shfl_down(ss, off);
    if (lane == 0) {
        double n = fmax(sqrt(ss), 1e-12);
        nx[row]  = (float)n;
        scx[row] = (float)(2.0 / n);
    }
}

// ---------------- main: split-bf16 MFMA scoring + exact top-2 + margin flagging.
// Each wave: 32 x-rows (2 groups of 16), X fragments register-resident,
// sweeps 4096 codes in 16-code blocks. No LDS, no barriers.
__launch_bounds__(256, 2)
__global__ void argmin_mfma_kernel(const float* __restrict__ x,
                                   const unsigned short* __restrict__ ch,
                                   const unsigned short* __restrict__ cl,
                                   const float* __restrict__ c2,
                                   const float* __restrict__ scx,
                                   int* __restrict__ idx_out,
                                   int* __restrict__ counter,
                                   int* __restrict__ rowlist) {
    int lane = threadIdx.x & 63;
    int wave = threadIdx.x >> 6;
    int col  = lane & 15;
    int kq   = lane >> 4;                 // 0..3
    int xbase = blockIdx.x * 128 + wave * 32;

    // ---- load + split X fragments (raw x; the 2/||x|| scale applies at epilogue)
    short8v bh[2][8], bl[2][8];
    #pragma unroll
    for (int g = 0; g < 2; g++) {
        int row = xbase + g * 16 + col;
        const float* xr = x + (size_t)row * DIM + kq * 8;
        #pragma unroll
        for (int s = 0; s < 8; s++) {
            float4 f0 = *(const float4*)(xr + s * 32);
            float4 f1 = *(const float4*)(xr + s * 32 + 4);
            float e[8] = {f0.x, f0.y, f0.z, f0.w, f1.x, f1.y, f1.z, f1.w};
            short8v h, l;
            #pragma unroll
            for (int j = 0; j < 8; j++) {
                unsigned short hb = f2bf(e[j]);
                h[j] = (short)hb;
                l[j] = (short)f2bf(e[j] - bf2f(hb));
            }
            bh[g][s] = h;
            bl[g][s] = l;
        }
    }
    float scr0 = scx[xbase + col];
    float scr1 = scx[xbase + 16 + col];

    // per-thread exact best-2 over this thread's code stream (per row-group)
    float s1a = 3.4e38f, s2a = 3.4e38f, s1b = 3.4e38f, s2b = 3.4e38f;
    int   i1a = 0x7fffffff, i1b = 0x7fffffff;

    for (int cb = 0; cb < NCODE / 16; cb++) {
        int cbb = cb * 16;
        const short8v* pah = (const short8v*)ch + ((size_t)(cbb + col) * 32 + kq);
        const short8v* pal = (const short8v*)cl + ((size_t)(cbb + col) * 32 + kq);
        float4v acc0 = {0.f, 0.f, 0.f, 0.f};
        float4v acc1 = {0.f, 0.f, 0.f, 0.f};
        #pragma unroll
        for (int s = 0; s < 8; s++) {
            short8v ah = pah[s * 4];
            short8v al = pal[s * 4];
            acc0 = __builtin_amdgcn_mfma_f32_16x16x32_bf16(ah, bh[0][s], acc0, 0, 0, 0);
            acc1 = __builtin_amdgcn_mfma_f32_16x16x32_bf16(ah, bh[1][s], acc1, 0, 0, 0);
            acc0 = __builtin_amdgcn_mfma_f32_16x16x32_bf16(ah, bl[0][s], acc0, 0, 0, 0);
            acc1 = __builtin_amdgcn_mfma_f32_16x16x32_bf16(ah, bl[1][s], acc1, 0, 0, 0);
            acc0 = __builtin_amdgcn_mfma_f32_16x16x32_bf16(al, bh[0][s], acc0, 0, 0, 0);
            acc1 = __builtin_amdgcn_mfma_f32_16x16x32_bf16(al, bh[1][s], acc1, 0, 0, 0);
        }
        // C/D layout: col=lane&15 (x-row), row=(lane>>4)*4+reg (code)  [m89/m91]
        float4v cc = *(const float4v*)(c2 + cbb + kq * 4);
        #pragma unroll
        for (int r = 0; r < 4; r++) {
            int ci = cbb + kq * 4 + r;   // ascending -> strict < keeps lowest index
            float sa = cc[r] - scr0 * acc0[r];
            if (sa < s1a) { s2a = s1a; s1a = sa; i1a = ci; }
            else if (sa < s2a) s2a = sa;
            float sb = cc[r] - scr1 * acc1[r];
            if (sb < s1b) { s2b = s1b; s1b = sb; i1b = ci; }
            else if (sb < s2b) s2b = sb;
        }
    }

    // exact global top-2 merge across the 4 lanes sharing this x-row (xor 16, 32)
    #pragma unroll
    for (int m = 16; m <= 32; m <<= 1) {
        float o1, o2; int oi;
        o1 = __shfl_xor(s1a, m); oi = __shfl_xor(i1a, m); o2 = __shfl_xor(s2a, m);
        if (o1 < s1a || (o1 == s1a && oi < i1a)) { s2a = fminf(s1a, o2); s1a = o1; i1a = oi; }
        else                                      { s2a = fminf(o1, s2a); }
        o1 = __shfl_xor(s1b, m); oi = __shfl_xor(i1b, m); o2 = __shfl_xor(s2b, m);
        if (o1 < s1b || (o1 == s1b && oi < i1b)) { s2b = fminf(s1b, o2); s1b = o1; i1b = oi; }
        else                                      { s2b = fminf(o1, s2b); }
    }
    if (lane < 16) {
        int row = xbase + lane;
        idx_out[row] = i1a;
        if (s2a - s1a < MARGIN) { int slot = atomicAdd(counter, 1); rowlist[slot] = row; }
        row += 16;
        idx_out[row] = i1b;
        if (s2b - s1b < MARGIN) { int slot = atomicAdd(counter, 1); rowlist[slot] = row; }
    }
}

// ---------------- f64 exact rescore for near-tie rows (full 4096-code scan)
__global__ void fixup_kernel(const float* __restrict__ x,
                             const float* __restrict__ cb,
                             const double* __restrict__ c2d,
                             const double* __restrict__ nd,
                             const int* __restrict__ counter,
                             const int* __restrict__ rowlist,
                             int* __restrict__ idxv) {
    __shared__ double xs[DIM];
    __shared__ double rn[4];
    __shared__ double rs[4];
    __shared__ int    ri[4];
    int t = threadIdx.x, lane = t & 63, w = t >> 6;
    int cnt = counter[0];
    for (int li = blockIdx.x; li < cnt; li += gridDim.x) {
        int row = rowlist[li];
        double xv = (double)x[(size_t)row * DIM + t];
        double ss = xv * xv;
        #pragma unroll
        for (int off = 32; off > 0; off >>= 1) ss += __shfl_down(ss, off);
        if (lane == 0) rn[w] = ss;
        xs[t] = xv;
        __syncthreads();
        double xnorm = fmax(sqrt(rn[0] + rn[1] + rn[2] + rn[3]), 1e-12);
        double isx = 2.0 / xnorm;
        double bs = 1e300; int bi = 0x7fffffff;
        for (int k0 = 0; k0 < NCODE / 256; k0++) {
            int k = k0 * 256 + t;
            const float4* cr = (const float4*)(cb + (size_t)k * DIM);
            double dot = 0.0;
            #pragma unroll 8
            for (int d4 = 0; d4 < DIM / 4; d4++) {
                float4 c = cr[d4];
                dot += (double)c.x * xs[d4 * 4 + 0] + (double)c.y * xs[d4 * 4 + 1]
                     + (double)c.z * xs[d4 * 4 + 2] + (double)c.w * xs[d4 * 4 + 3];
            }
            double s = c2d[k] - isx * dot / nd[k];
            if (s < bs || (s == bs && k < bi)) { bs = s; bi = k; }
        }
        #pragma unroll
        for (int m = 1; m < 64; m <<= 1) {
            double os = __shfl_xor(bs, m);
            int   oi = __shfl_xor(bi, m);
            if (os < bs || (os == bs && oi < bi)) { bs = os; bi = oi; }
        }
        if (lane == 0) { rs[w] = bs; ri[w] = bi; }
        __syncthreads();
        if (t == 0) {
            for (int ww = 1; ww < 4; ww++)
                if (rs[ww] < bs || (rs[ww] == bs && ri[ww] < bi)) { bs = rs[ww]; bi = ri[ww]; }
            idxv[row] = bi;
        }
        __syncthreads();
    }
}

// ---------------- gather + per-row loss partial
__global__ void gather_loss_kernel(const float* __restrict__ x,
                                   const float* __restrict__ cbn,
                                   const float* __restrict__ c2,
                                   const float* __restrict__ nx,
                                   const int* __restrict__ idxv,
                                   float* __restrict__ out_q,
                                   float* __restrict__ out_idxf,
                                   float* __restrict__ partials) {
    int row = blockIdx.x;
    int t = threadIdx.x;
    int iv = idxv[row];
    float q = cbn[(size_t)iv * DIM + t];
    float qn = fmaxf(sqrtf(c2[iv]), 1e-12f);
    q = q / qn;
    float xv = x[(size_t)row * DIM + t] / nx[row];
    out_q[(size_t)row * DIM + t] = q;
    float d = q - xv;
    float ss = d * d;
    __shared__ float red[4];
    #pragma unroll
    for (int off = 32; off > 0; off >>= 1) ss += __shfl_down(ss, off);
    if ((t & 63) == 0) red[t >> 6] = ss;
    __syncthreads();
    if (t == 0) {
        partials[row] = red[0] + red[1] + red[2] + red[3];
        out_idxf[row] = (float)iv;
    }
}

// ---------------- final deterministic loss reduction
__global__ void loss_reduce_kernel(const float* __restrict__ partials,
                                   float* __restrict__ out_loss) {
    int t = threadIdx.x;
    float s = 0.0f;
    for (int i = t; i < N_ROWS; i += 256) s += partials[i];
    __shared__ float red[4];
    #pragma unroll
    for (int off = 32; off > 0; off >>= 1) s += __shfl_down(s, off);
    if ((t & 63) == 0) red[t >> 6] = s;
    __syncthreads();
    if (t == 0) out_loss[0] = 1.25f * (red[0] + red[1] + red[2] + red[3]) / (float)(N_ROWS * DIM);
}

extern "C" void kernel_launch(void* const* d_in, const int* in_sizes, int n_in,
                              void* d_out, int out_size, void* d_ws, size_t ws_size,
                              hipStream_t stream) {
    const float* x  = (const float*)d_in[0];
    const float* cb = (const float*)d_in[1];
    float* out = (float*)d_out;

    double* c2d = (double*)d_ws;                      // 4096 doubles
    double* nd  = c2d + NCODE;                        // 4096 doubles
    float* cbn = (float*)(nd + NCODE);                // 4096*256 floats
    float* c2  = cbn + (size_t)NCODE * DIM;           // 4096
    float* nx  = c2 + NCODE;                          // 65536
    float* scx = nx + N_ROWS;                         // 65536
    int*   idxv = (int*)(scx + N_ROWS);               // 65536
    float* partials = (float*)(idxv + N_ROWS);        // 65536
    int*   counter  = (int*)(partials + N_ROWS);      // 4 ints
    int*   rowlist  = counter + 4;                    // 65536
    unsigned short* ch = (unsigned short*)(rowlist + N_ROWS);   // 4096*256 ushort
    unsigned short* cl = ch + (size_t)NCODE * DIM;              // 4096*256 ushort

    float* out_q    = out;
    float* out_loss = out + (size_t)N_ROWS * DIM;
    float* out_idxf = out_loss + 1;

    hipLaunchKernelGGL(cb_norm_kernel, dim3(NCODE), dim3(256), 0, stream,
                       cb, cbn, ch, cl, c2, c2d, nd);
    hipLaunchKernelGGL(x_norm_kernel, dim3(N_ROWS / 4), dim3(256), 0, stream, x, nx, scx, counter);
    hipLaunchKernelGGL(argmin_mfma_kernel, dim3(N_ROWS / 128), dim3(256), 0, stream,
                       x, ch, cl, c2, scx, idxv, counter, rowlist);
    hipLaunchKernelGGL(fixup_kernel, dim3(128), dim3(256), 0, stream,
                       x, cb, c2d, nd, counter, rowlist, idxv);
    hipLaunchKernelGGL(gather_loss_kernel, dim3(N_ROWS), dim3(256), 0, stream,
                       x, cbn, c2, nx, idxv, out_q, out_idxf, partials);
    hipLaunchKernelGGL(loss_reduce_kernel, dim3(1), dim3(256), 0, stream,
                       partials, out_loss);
}

// Round 7
// 1178.403 us; speedup vs baseline: 2.5898x; 1.3576x over previous
//
#include <hip/hip_runtime.h>
#include <math.h>

#define N_ROWS 65536
#define DIM    256
#define NCODE  4096
#define MARGIN 2e-4f
#define TILE_C 32               // codes per LDS tile
#define NT     (NCODE / TILE_C) // 128 tiles

typedef __attribute__((ext_vector_type(8))) short short8v;
typedef __attribute__((ext_vector_type(4))) float float4v;

__device__ inline unsigned short f2bf(float f) {
    unsigned u = __float_as_uint(f);
    unsigned r = (u + 0x7fffu + ((u >> 16) & 1u)) >> 16;
    return (unsigned short)r;
}
__device__ inline float bf2f(unsigned short h) {
    return __uint_as_float(((unsigned)h) << 16);
}

// ---------------- codebook normalize (f64 norm): cbn fp32, bf16 split (ch,cl), c2/c2d/nd
__global__ void cb_norm_kernel(const float* __restrict__ cb,
                               float* __restrict__ cbn,
                               unsigned short* __restrict__ ch,
                               unsigned short* __restrict__ cl,
                               float* __restrict__ c2,
                               double* __restrict__ c2d,
                               double* __restrict__ nd) {
    int k = blockIdx.x;
    int t = threadIdx.x;
    float v = cb[k * DIM + t];
    double dv = (double)v;
    double ss = dv * dv;
    __shared__ double red2[4], red3[4], redn[4];
    #pragma unroll
    for (int off = 32; off > 0; off >>= 1) ss += __shfl_down(ss, off);
    if ((t & 63) == 0) redn[t >> 6] = ss;
    __syncthreads();
    double S = redn[0] + redn[1] + redn[2] + redn[3];
    double nrm = fmax(sqrt(S), 1e-12);
    double cq = dv / nrm;
    float cf = (float)cq;
    cbn[k * DIM + t] = cf;
    unsigned short hb = f2bf(cf);
    ch[k * DIM + t] = hb;
    cl[k * DIM + t] = f2bf(cf - bf2f(hb));
    double s2 = (double)cf * (double)cf;
    double s3 = cq * cq;
    #pragma unroll
    for (int off = 32; off > 0; off >>= 1) {
        s2 += __shfl_down(s2, off);
        s3 += __shfl_down(s3, off);
    }
    if ((t & 63) == 0) { red2[t >> 6] = s2; red3[t >> 6] = s3; }
    __syncthreads();
    if (t == 0) {
        c2[k]  = (float)(red2[0] + red2[1] + red2[2] + red2[3]);
        c2d[k] = red3[0] + red3[1] + red3[2] + red3[3];
        nd[k]  = nrm;
    }
}

// ---------------- per-row x norms in f64; also zero the fixup counter
__global__ void x_norm_kernel(const float* __restrict__ x,
                              float* __restrict__ nx,
                              float* __restrict__ scx,
                              int* __restrict__ counter) {
    if (blockIdx.x == 0 && threadIdx.x == 0) counter[0] = 0;
    int w = threadIdx.x >> 6;
    int lane = threadIdx.x & 63;
    int row = blockIdx.x * 4 + w;
    float4 v = ((const float4*)(x + (size_t)row * DIM))[lane];
    double ss = (double)v.x * v.x + (double)v.y * v.y
              + (double)v.z * v.z + (double)v.w * v.w;
    #pragma unroll
    for (int off = 32; off > 0; off >>= 1) ss += __shfl_down(ss, off);
    if (lane == 0) {
        double n = fmax(sqrt(ss), 1e-12);
        nx[row]  = (float)n;
        scx[row] = (float)(2.0 / n);
    }
}

// ---------------- main: split-bf16 MFMA scoring, LDS-shared codebook tiles,
// double-buffered T14 staging. Block = 4 waves = 128 x-rows; wave = 32 rows.
__launch_bounds__(256, 2)
__global__ void argmin_mfma_kernel(const float* __restrict__ x,
                                   const unsigned short* __restrict__ ch,
                                   const unsigned short* __restrict__ cl,
                                   const float* __restrict__ c2,
                                   const float* __restrict__ scx,
                                   int* __restrict__ idx_out,
                                   int* __restrict__ counter,
                                   int* __restrict__ rowlist) {
    // per-buffer: 1024 chunks of 16B, layout chunk q = c*32 + k  (c=dim-chunk, k=code)
    __shared__ short Hs[2][8192];
    __shared__ short Ls[2][8192];

    int tid  = threadIdx.x;
    int lane = tid & 63;
    int wave = tid >> 6;
    int col  = lane & 15;
    int kq   = lane >> 4;                 // 0..3
    int xbase = blockIdx.x * 128 + wave * 32;

    // ---- load + split X fragments (raw x; 2/||x|| scale applied at epilogue)
    short8v bh[2][8], bl[2][8];
    #pragma unroll
    for (int g = 0; g < 2; g++) {
        int row = xbase + g * 16 + col;
        const float* xr = x + (size_t)row * DIM + kq * 8;
        #pragma unroll
        for (int s = 0; s < 8; s++) {
            float4 f0 = *(const float4*)(xr + s * 32);
            float4 f1 = *(const float4*)(xr + s * 32 + 4);
            float e[8] = {f0.x, f0.y, f0.z, f0.w, f1.x, f1.y, f1.z, f1.w};
            short8v h, l;
            #pragma unroll
            for (int j = 0; j < 8; j++) {
                unsigned short hb = f2bf(e[j]);
                h[j] = (short)hb;
                l[j] = (short)f2bf(e[j] - bf2f(hb));
            }
            bh[g][s] = h;
            bl[g][s] = l;
        }
    }
    float scr0 = scx[xbase + col];
    float scr1 = scx[xbase + 16 + col];

    float s1a = 3.4e38f, s2a = 3.4e38f, s1b = 3.4e38f, s2b = 3.4e38f;
    int   i1a = 0x7fffffff, i1b = 0x7fffffff;

    // ---- stage tile 0 into buffer 0
    {
        #pragma unroll
        for (int j = 0; j < 4; j++) {
            int q = j * 256 + tid;       // chunk id: c = q>>5, k = q&31
            int c = q >> 5, k = q & 31;
            size_t go = ((size_t)k * DIM + c * 8) * 2;   // cbb=0
            *(uint4*)((char*)Hs[0] + (size_t)q * 16) = *(const uint4*)((const char*)ch + go);
            *(uint4*)((char*)Ls[0] + (size_t)q * 16) = *(const uint4*)((const char*)cl + go);
        }
    }
    __syncthreads();

    int cur = 0;
    for (int t = 0; t < NT; t++) {
        int cbb = t * TILE_C;

        // ---- issue next tile's global loads (latency hides under MFMA below)
        uint4 nh[4], nl[4];
        if (t + 1 < NT) {
            int nb = cbb + TILE_C;
            #pragma unroll
            for (int j = 0; j < 4; j++) {
                int q = j * 256 + tid;
                int c = q >> 5, k = q & 31;
                size_t go = ((size_t)(nb + k) * DIM + c * 8) * 2;
                nh[j] = *(const uint4*)((const char*)ch + go);
                nl[j] = *(const uint4*)((const char*)cl + go);
            }
        }

        // ---- compute current tile from LDS
        const short* hb = Hs[cur];
        const short* lb = Ls[cur];
        #pragma unroll
        for (int sb = 0; sb < 2; sb++) {
            int kk = sb * 16 + col;
            float4v a0 = {0.f, 0.f, 0.f, 0.f};
            float4v a1 = {0.f, 0.f, 0.f, 0.f};
            #pragma unroll
            for (int s = 0; s < 8; s++) {
                int q = (s * 4 + kq) * 32 + kk;
                short8v ah = *(const short8v*)(hb + (size_t)q * 8);
                short8v al = *(const short8v*)(lb + (size_t)q * 8);
                a0 = __builtin_amdgcn_mfma_f32_16x16x32_bf16(ah, bh[0][s], a0, 0, 0, 0);
                a1 = __builtin_amdgcn_mfma_f32_16x16x32_bf16(ah, bh[1][s], a1, 0, 0, 0);
                a0 = __builtin_amdgcn_mfma_f32_16x16x32_bf16(ah, bl[0][s], a0, 0, 0, 0);
                a1 = __builtin_amdgcn_mfma_f32_16x16x32_bf16(ah, bl[1][s], a1, 0, 0, 0);
                a0 = __builtin_amdgcn_mfma_f32_16x16x32_bf16(al, bh[0][s], a0, 0, 0, 0);
                a1 = __builtin_amdgcn_mfma_f32_16x16x32_bf16(al, bh[1][s], a1, 0, 0, 0);
            }
            int cb16 = cbb + sb * 16;
            float4v cc = *(const float4v*)(c2 + cb16 + kq * 4);
            #pragma unroll
            for (int r = 0; r < 4; r++) {
                int ci = cb16 + kq * 4 + r;   // ascending -> strict < keeps lowest index
                float sa = cc[r] - scr0 * a0[r];
                if (sa < s1a) { s2a = s1a; s1a = sa; i1a = ci; }
                else if (sa < s2a) s2a = sa;
                float sbv = cc[r] - scr1 * a1[r];
                if (sbv < s1b) { s2b = s1b; s1b = sbv; i1b = ci; }
                else if (sbv < s2b) s2b = sbv;
            }
        }

        // ---- write prefetched tile into the other buffer
        if (t + 1 < NT) {
            __syncthreads();
            int nxt = cur ^ 1;
            #pragma unroll
            for (int j = 0; j < 4; j++) {
                int q = j * 256 + tid;
                *(uint4*)((char*)Hs[nxt] + (size_t)q * 16) = nh[j];
                *(uint4*)((char*)Ls[nxt] + (size_t)q * 16) = nl[j];
            }
            __syncthreads();
            cur = nxt;
        }
    }

    // exact global top-2 merge across the 4 lanes sharing this x-row (xor 16, 32)
    #pragma unroll
    for (int m = 16; m <= 32; m <<= 1) {
        float o1, o2; int oi;
        o1 = __shfl_xor(s1a, m); oi = __shfl_xor(i1a, m); o2 = __shfl_xor(s2a, m);
        if (o1 < s1a || (o1 == s1a && oi < i1a)) { s2a = fminf(s1a, o2); s1a = o1; i1a = oi; }
        else                                      { s2a = fminf(o1, s2a); }
        o1 = __shfl_xor(s1b, m); oi = __shfl_xor(i1b, m); o2 = __shfl_xor(s2b, m);
        if (o1 < s1b || (o1 == s1b && oi < i1b)) { s2b = fminf(s1b, o2); s1b = o1; i1b = oi; }
        else                                      { s2b = fminf(o1, s2b); }
    }
    if (lane < 16) {
        int row = xbase + lane;
        idx_out[row] = i1a;
        if (s2a - s1a < MARGIN) { int slot = atomicAdd(counter, 1); rowlist[slot] = row; }
        row += 16;
        idx_out[row] = i1b;
        if (s2b - s1b < MARGIN) { int slot = atomicAdd(counter, 1); rowlist[slot] = row; }
    }
}

// ---------------- f64 exact rescore for near-tie rows (full 4096-code scan)
__global__ void fixup_kernel(const float* __restrict__ x,
                             const float* __restrict__ cb,
                             const double* __restrict__ c2d,
                             const double* __restrict__ nd,
                             const int* __restrict__ counter,
                             const int* __restrict__ rowlist,
                             int* __restrict__ idxv) {
    __shared__ double xs[DIM];
    __shared__ double rn[4];
    __shared__ double rs[4];
    __shared__ int    ri[4];
    int t = threadIdx.x, lane = t & 63, w = t >> 6;
    int cnt = counter[0];
    for (int li = blockIdx.x; li < cnt; li += gridDim.x) {
        int row = rowlist[li];
        double xv = (double)x[(size_t)row * DIM + t];
        double ss = xv * xv;
        #pragma unroll
        for (int off = 32; off > 0; off >>= 1) ss += __shfl_down(ss, off);
        if (lane == 0) rn[w] = ss;
        xs[t] = xv;
        __syncthreads();
        double xnorm = fmax(sqrt(rn[0] + rn[1] + rn[2] + rn[3]), 1e-12);
        double isx = 2.0 / xnorm;
        double bs = 1e300; int bi = 0x7fffffff;
        for (int k0 = 0; k0 < NCODE / 256; k0++) {
            int k = k0 * 256 + t;
            const float4* cr = (const float4*)(cb + (size_t)k * DIM);
            double dot = 0.0;
            #pragma unroll 8
            for (int d4 = 0; d4 < DIM / 4; d4++) {
                float4 c = cr[d4];
                dot += (double)c.x * xs[d4 * 4 + 0] + (double)c.y * xs[d4 * 4 + 1]
                     + (double)c.z * xs[d4 * 4 + 2] + (double)c.w * xs[d4 * 4 + 3];
            }
            double s = c2d[k] - isx * dot / nd[k];
            if (s < bs || (s == bs && k < bi)) { bs = s; bi = k; }
        }
        #pragma unroll
        for (int m = 1; m < 64; m <<= 1) {
            double os = __shfl_xor(bs, m);
            int   oi = __shfl_xor(bi, m);
            if (os < bs || (os == bs && oi < bi)) { bs = os; bi = oi; }
        }
        if (lane == 0) { rs[w] = bs; ri[w] = bi; }
        __syncthreads();
        if (t == 0) {
            for (int ww = 1; ww < 4; ww++)
                if (rs[ww] < bs || (rs[ww] == bs && ri[ww] < bi)) { bs = rs[ww]; bi = ri[ww]; }
            idxv[row] = bi;
        }
        __syncthreads();
    }
}

// ---------------- gather + per-row loss partial (vectorized: 4 rows/block, float4)
__global__ void gather_loss_kernel(const float* __restrict__ x,
                                   const float* __restrict__ cbn,
                                   const float* __restrict__ c2,
                                   const float* __restrict__ nx,
                                   const int* __restrict__ idxv,
                                   float* __restrict__ out_q,
                                   float* __restrict__ out_idxf,
                                   float* __restrict__ partials) {
    int w = threadIdx.x >> 6, lane = threadIdx.x & 63;
    int row = blockIdx.x * 4 + w;
    int iv = idxv[row];
    float inv_qn = 1.0f / fmaxf(sqrtf(c2[iv]), 1e-12f);
    float inx = 1.0f / nx[row];
    float4 q4 = ((const float4*)(cbn + (size_t)iv * DIM))[lane];
    float4 x4 = ((const float4*)(x + (size_t)row * DIM))[lane];
    float4 qq;
    qq.x = q4.x * inv_qn; qq.y = q4.y * inv_qn;
    qq.z = q4.z * inv_qn; qq.w = q4.w * inv_qn;
    ((float4*)(out_q + (size_t)row * DIM))[lane] = qq;
    float dx = qq.x - x4.x * inx;
    float dy = qq.y - x4.y * inx;
    float dz = qq.z - x4.z * inx;
    float dw = qq.w - x4.w * inx;
    float ss = dx * dx + dy * dy + dz * dz + dw * dw;
    #pragma unroll
    for (int off = 32; off > 0; off >>= 1) ss += __shfl_down(ss, off);
    if (lane == 0) {
        partials[row] = ss;
        out_idxf[row] = (float)iv;
    }
}

// ---------------- final deterministic loss reduction
__global__ void loss_reduce_kernel(const float* __restrict__ partials,
                                   float* __restrict__ out_loss) {
    int t = threadIdx.x;
    float s = 0.0f;
    for (int i = t; i < N_ROWS; i += 256) s += partials[i];
    __shared__ float red[4];
    #pragma unroll
    for (int off = 32; off > 0; off >>= 1) s += __shfl_down(s, off);
    if ((t & 63) == 0) red[t >> 6] = s;
    __syncthreads();
    if (t == 0) out_loss[0] = 1.25f * (red[0] + red[1] + red[2] + red[3]) / (float)(N_ROWS * DIM);
}

extern "C" void kernel_launch(void* const* d_in, const int* in_sizes, int n_in,
                              void* d_out, int out_size, void* d_ws, size_t ws_size,
                              hipStream_t stream) {
    const float* x  = (const float*)d_in[0];
    const float* cb = (const float*)d_in[1];
    float* out = (float*)d_out;

    double* c2d = (double*)d_ws;                      // 4096 doubles
    double* nd  = c2d + NCODE;                        // 4096 doubles
    float* cbn = (float*)(nd + NCODE);                // 4096*256 floats
    float* c2  = cbn + (size_t)NCODE * DIM;           // 4096
    float* nx  = c2 + NCODE;                          // 65536
    float* scx = nx + N_ROWS;                         // 65536
    int*   idxv = (int*)(scx + N_ROWS);               // 65536
    float* partials = (float*)(idxv + N_ROWS);        // 65536
    int*   counter  = (int*)(partials + N_ROWS);      // 4 ints
    int*   rowlist  = counter + 4;                    // 65536
    unsigned short* ch = (unsigned short*)(rowlist + N_ROWS);   // 4096*256 ushort
    unsigned short* cl = ch + (size_t)NCODE * DIM;              // 4096*256 ushort

    float* out_q    = out;
    float* out_loss = out + (size_t)N_ROWS * DIM;
    float* out_idxf = out_loss + 1;

    hipLaunchKernelGGL(cb_norm_kernel, dim3(NCODE), dim3(256), 0, stream,
                       cb, cbn, ch, cl, c2, c2d, nd);
    hipLaunchKernelGGL(x_norm_kernel, dim3(N_ROWS / 4), dim3(256), 0, stream, x, nx, scx, counter);
    hipLaunchKernelGGL(argmin_mfma_kernel, dim3(N_ROWS / 128), dim3(256), 0, stream,
                       x, ch, cl, c2, scx, idxv, counter, rowlist);
    hipLaunchKernelGGL(fixup_kernel, dim3(128), dim3(256), 0, stream,
                       x, cb, c2d, nd, counter, rowlist, idxv);
    hipLaunchKernelGGL(gather_loss_kernel, dim3(N_ROWS / 4), dim3(256), 0, stream,
                       x, cbn, c2, nx, idxv, out_q, out_idxf, partials);
    hipLaunchKernelGGL(loss_reduce_kernel, dim3(1), dim3(256), 0, stream,
                       partials, out_loss);
}

// Round 8
// 926.806 us; speedup vs baseline: 3.2929x; 1.2715x over previous
//
#include <hip/hip_runtime.h>
#include <math.h>

#define N_ROWS 65536
#define DIM    256
#define NCODE  4096
#define MARGIN 2e-4f
#define TILE_C 32
#define NTILE  (NCODE / TILE_C)   // 128

typedef __attribute__((ext_vector_type(8)))  short short8v;
typedef __attribute__((ext_vector_type(4)))  float float4v;
typedef __attribute__((ext_vector_type(16))) float f32x16;

__device__ inline unsigned short f2bf(float f) {
    unsigned u = __float_as_uint(f);
    unsigned r = (u + 0x7fffu + ((u >> 16) & 1u)) >> 16;
    return (unsigned short)r;
}
__device__ inline float bf2f(unsigned short h) {
    return __uint_as_float(((unsigned)h) << 16);
}
__device__ inline void gll16(const void* g, void* l) {
    __builtin_amdgcn_global_load_lds(
        (const __attribute__((address_space(1))) unsigned int*)g,
        (__attribute__((address_space(3))) unsigned int*)l, 16, 0, 0);
}

// ---------------- codebook normalize: cbn fp32, PACKED bf16 split chunks (pk), c2/c2d/nd
// pk chunk layout: [cb32][ks][hl] -> 1KB chunk; within chunk lane=(hi*32+klo), 8 elems.
// element (code k, dim t): cb32=k>>5, klo=k&31, ks=t>>4, hi=(t>>3)&1, j=t&7.
__global__ void cb_norm_kernel(const float* __restrict__ cb,
                               float* __restrict__ cbn,
                               unsigned short* __restrict__ pk,
                               float* __restrict__ c2,
                               double* __restrict__ c2d,
                               double* __restrict__ nd) {
    int k = blockIdx.x;
    int t = threadIdx.x;
    float v = cb[k * DIM + t];
    double dv = (double)v;
    double ss = dv * dv;
    __shared__ double red2[4], red3[4], redn[4];
    #pragma unroll
    for (int off = 32; off > 0; off >>= 1) ss += __shfl_down(ss, off);
    if ((t & 63) == 0) redn[t >> 6] = ss;
    __syncthreads();
    double S = redn[0] + redn[1] + redn[2] + redn[3];
    double nrm = fmax(sqrt(S), 1e-12);
    double cq = dv / nrm;
    float cf = (float)cq;
    cbn[k * DIM + t] = cf;
    unsigned short hb = f2bf(cf);
    unsigned short lb = f2bf(cf - bf2f(hb));
    {
        int cb32 = k >> 5, klo = k & 31, ks = t >> 4, hi = (t >> 3) & 1, j = t & 7;
        size_t ch = ((size_t)cb32 * 16 + ks) * 2;           // h-chunk id
        size_t slot = (size_t)(hi * 32 + klo) * 8 + j;
        pk[(ch + 0) * 512 + slot] = hb;
        pk[(ch + 1) * 512 + slot] = lb;
    }
    double s2 = (double)cf * (double)cf;
    double s3 = cq * cq;
    #pragma unroll
    for (int off = 32; off > 0; off >>= 1) {
        s2 += __shfl_down(s2, off);
        s3 += __shfl_down(s3, off);
    }
    if ((t & 63) == 0) { red2[t >> 6] = s2; red3[t >> 6] = s3; }
    __syncthreads();
    if (t == 0) {
        c2[k]  = (float)(red2[0] + red2[1] + red2[2] + red2[3]);
        c2d[k] = red3[0] + red3[1] + red3[2] + red3[3];
        nd[k]  = nrm;
    }
}

// ---------------- per-row x norms in f64; also zero the fixup counter
__global__ void x_norm_kernel(const float* __restrict__ x,
                              float* __restrict__ nx,
                              float* __restrict__ scx,
                              int* __restrict__ counter) {
    if (blockIdx.x == 0 && threadIdx.x == 0) counter[0] = 0;
    int w = threadIdx.x >> 6;
    int lane = threadIdx.x & 63;
    int row = blockIdx.x * 4 + w;
    float4 v = ((const float4*)(x + (size_t)row * DIM))[lane];
    double ss = (double)v.x * v.x + (double)v.y * v.y
              + (double)v.z * v.z + (double)v.w * v.w;
    #pragma unroll
    for (int off = 32; off > 0; off >>= 1) ss += __shfl_down(ss, off);
    if (lane == 0) {
        double n = fmax(sqrt(ss), 1e-12);
        nx[row]  = (float)n;
        scx[row] = (float)(2.0 / n);
    }
}

// ---------------- main: 32x32x16 split-bf16 MFMA, global_load_lds staging,
// linear conflict-free LDS, 1 barrier/tile. Wave = 32 rows; block = 128 rows.
__attribute__((amdgpu_waves_per_eu(2, 2)))
__global__ void __launch_bounds__(256)
argmin_mfma_kernel(const float* __restrict__ x,
                   const unsigned short* __restrict__ pk,
                   const float* __restrict__ c2,
                   const float* __restrict__ scx,
                   int* __restrict__ idx_out,
                   int* __restrict__ counter,
                   int* __restrict__ rowlist) {
    __shared__ unsigned short buf[2][16384];   // 2 x 32KB

    int tid  = threadIdx.x;
    int lane = tid & 63;
    int wave = tid >> 6;
    int cl31 = lane & 31;
    int hi   = lane >> 5;
    int xbase = blockIdx.x * 128 + wave * 32;

    // ---- load + split X fragments: B-frag row = lane&31, k = hi*8+j
    short8v bh[16], bl[16];
    const float* xr = x + (size_t)(xbase + cl31) * DIM + hi * 8;
    #pragma unroll
    for (int ks = 0; ks < 16; ks++) {
        float4 f0 = *(const float4*)(xr + ks * 16);
        float4 f1 = *(const float4*)(xr + ks * 16 + 4);
        float e[8] = {f0.x, f0.y, f0.z, f0.w, f1.x, f1.y, f1.z, f1.w};
        short8v h, l;
        #pragma unroll
        for (int j = 0; j < 8; j++) {
            unsigned short hb = f2bf(e[j]);
            h[j] = (short)hb;
            l[j] = (short)f2bf(e[j] - bf2f(hb));
        }
        bh[ks] = h;
        bl[ks] = l;
    }
    float scr = scx[xbase + cl31];

    float s1 = 3.4e38f, s2 = 3.4e38f;
    int   i1 = 0x7fffffff;

    // ---- stage tile 0 (each wave: 8 chunks, linear 1KB each)
    {
        const unsigned short* src = pk + ((size_t)wave * 8) * 512 + lane * 8;
        unsigned short* dst = &buf[0][(wave * 8) * 512];
        #pragma unroll
        for (int i = 0; i < 8; i++) gll16(src + i * 512, dst + i * 512);
    }
    __syncthreads();

    int cur = 0;
    for (int t = 0; t < NTILE; t++) {
        int cbb = t * TILE_C;

        // ---- issue next tile's async stages into the other buffer
        if (t + 1 < NTILE) {
            const unsigned short* src =
                pk + ((size_t)(t + 1) * 32 + wave * 8) * 512 + lane * 8;
            unsigned short* dst = &buf[cur ^ 1][(wave * 8) * 512];
            #pragma unroll
            for (int i = 0; i < 8; i++) gll16(src + i * 512, dst + i * 512);
        }

        // ---- 48 MFMA from LDS (A: code row = lane&31, k = hi*8+j -> linear reads)
        const unsigned short* cbuf = &buf[cur][0];
        f32x16 acc = {0.f,0.f,0.f,0.f,0.f,0.f,0.f,0.f,0.f,0.f,0.f,0.f,0.f,0.f,0.f,0.f};
        #pragma unroll
        for (int ks = 0; ks < 16; ks++) {
            short8v ah = *(const short8v*)(cbuf + (size_t)(ks * 2 + 0) * 512 + lane * 8);
            short8v al = *(const short8v*)(cbuf + (size_t)(ks * 2 + 1) * 512 + lane * 8);
            acc = __builtin_amdgcn_mfma_f32_32x32x16_bf16(ah, bh[ks], acc, 0, 0, 0);
            acc = __builtin_amdgcn_mfma_f32_32x32x16_bf16(ah, bl[ks], acc, 0, 0, 0);
            acc = __builtin_amdgcn_mfma_f32_32x32x16_bf16(al, bh[ks], acc, 0, 0, 0);
        }

        // ---- epilogue: scores = c2 - scr*dot; exact best2 with wave-skip
        const float4v* c2p = (const float4v*)(c2 + cbb + hi * 4);
        float4v gq0 = c2p[0], gq1 = c2p[2], gq2 = c2p[4], gq3 = c2p[6];
        float sv[16];
        float mn = 3.4e38f;
        #pragma unroll
        for (int g = 0; g < 4; g++) {
            float4v gg = (g == 0) ? gq0 : (g == 1) ? gq1 : (g == 2) ? gq2 : gq3;
            #pragma unroll
            for (int q = 0; q < 4; q++) {
                float s = gg[q] - scr * acc[g * 4 + q];
                sv[g * 4 + q] = s;
                mn = fminf(mn, s);
            }
        }
        if (!__all(mn >= s2)) {
            #pragma unroll
            for (int g = 0; g < 4; g++) {
                #pragma unroll
                for (int q = 0; q < 4; q++) {
                    float s = sv[g * 4 + q];
                    int ci = cbb + q + 8 * g + 4 * hi;   // ascending in (g,q)
                    if (s < s1) { s2 = s1; s1 = s; i1 = ci; }
                    else if (s < s2) s2 = s;
                }
            }
        }

        __syncthreads();   // drains gll vmcnt per-wave; all waves done with cur
        cur ^= 1;
    }

    // ---- merge the two lane-halves (same row, disjoint codes)
    {
        float o1 = __shfl_xor(s1, 32);
        int   oi = __shfl_xor(i1, 32);
        float o2 = __shfl_xor(s2, 32);
        if (o1 < s1 || (o1 == s1 && oi < i1)) { s2 = fminf(s1, o2); s1 = o1; i1 = oi; }
        else                                   { s2 = fminf(o1, s2); }
    }
    if (lane < 32) {
        int row = xbase + lane;
        idx_out[row] = i1;
        if (s2 - s1 < MARGIN) { int slot = atomicAdd(counter, 1); rowlist[slot] = row; }
    }
}

// ---------------- f64 exact rescore for near-tie rows (full 4096-code scan)
__global__ void fixup_kernel(const float* __restrict__ x,
                             const float* __restrict__ cb,
                             const double* __restrict__ c2d,
                             const double* __restrict__ nd,
                             const int* __restrict__ counter,
                             const int* __restrict__ rowlist,
                             int* __restrict__ idxv) {
    __shared__ double xs[DIM];
    __shared__ double rn[4];
    __shared__ double rs[4];
    __shared__ int    ri[4];
    int t = threadIdx.x, lane = t & 63, w = t >> 6;
    int cnt = counter[0];
    for (int li = blockIdx.x; li < cnt; li += gridDim.x) {
        int row = rowlist[li];
        double xv = (double)x[(size_t)row * DIM + t];
        double ss = xv * xv;
        #pragma unroll
        for (int off = 32; off > 0; off >>= 1) ss += __shfl_down(ss, off);
        if (lane == 0) rn[w] = ss;
        xs[t] = xv;
        __syncthreads();
        double xnorm = fmax(sqrt(rn[0] + rn[1] + rn[2] + rn[3]), 1e-12);
        double isx = 2.0 / xnorm;
        double bs = 1e300; int bi = 0x7fffffff;
        for (int k0 = 0; k0 < NCODE / 256; k0++) {
            int k = k0 * 256 + t;
            const float4* cr = (const float4*)(cb + (size_t)k * DIM);
            double dot = 0.0;
            #pragma unroll 8
            for (int d4 = 0; d4 < DIM / 4; d4++) {
                float4 c = cr[d4];
                dot += (double)c.x * xs[d4 * 4 + 0] + (double)c.y * xs[d4 * 4 + 1]
                     + (double)c.z * xs[d4 * 4 + 2] + (double)c.w * xs[d4 * 4 + 3];
            }
            double s = c2d[k] - isx * dot / nd[k];
            if (s < bs || (s == bs && k < bi)) { bs = s; bi = k; }
        }
        #pragma unroll
        for (int m = 1; m < 64; m <<= 1) {
            double os = __shfl_xor(bs, m);
            int   oi = __shfl_xor(bi, m);
            if (os < bs || (os == bs && oi < bi)) { bs = os; bi = oi; }
        }
        if (lane == 0) { rs[w] = bs; ri[w] = bi; }
        __syncthreads();
        if (t == 0) {
            for (int ww = 1; ww < 4; ww++)
                if (rs[ww] < bs || (rs[ww] == bs && ri[ww] < bi)) { bs = rs[ww]; bi = ri[ww]; }
            idxv[row] = bi;
        }
        __syncthreads();
    }
}

// ---------------- gather + per-row loss partial (4 rows/block, float4)
__global__ void gather_loss_kernel(const float* __restrict__ x,
                                   const float* __restrict__ cbn,
                                   const float* __restrict__ c2,
                                   const float* __restrict__ nx,
                                   const int* __restrict__ idxv,
                                   float* __restrict__ out_q,
                                   float* __restrict__ out_idxf,
                                   float* __restrict__ partials) {
    int w = threadIdx.x >> 6, lane = threadIdx.x & 63;
    int row = blockIdx.x * 4 + w;
    int iv = idxv[row];
    float inv_qn = 1.0f / fmaxf(sqrtf(c2[iv]), 1e-12f);
    float inx = 1.0f / nx[row];
    float4 q4 = ((const float4*)(cbn + (size_t)iv * DIM))[lane];
    float4 x4 = ((const float4*)(x + (size_t)row * DIM))[lane];
    float4 qq;
    qq.x = q4.x * inv_qn; qq.y = q4.y * inv_qn;
    qq.z = q4.z * inv_qn; qq.w = q4.w * inv_qn;
    ((float4*)(out_q + (size_t)row * DIM))[lane] = qq;
    float dx = qq.x - x4.x * inx;
    float dy = qq.y - x4.y * inx;
    float dz = qq.z - x4.z * inx;
    float dw = qq.w - x4.w * inx;
    float ss = dx * dx + dy * dy + dz * dz + dw * dw;
    #pragma unroll
    for (int off = 32; off > 0; off >>= 1) ss += __shfl_down(ss, off);
    if (lane == 0) {
        partials[row] = ss;
        out_idxf[row] = (float)iv;
    }
}

// ---------------- final deterministic loss reduction
__global__ void loss_reduce_kernel(const float* __restrict__ partials,
                                   float* __restrict__ out_loss) {
    int t = threadIdx.x;
    float s = 0.0f;
    for (int i = t; i < N_ROWS; i += 256) s += partials[i];
    __shared__ float red[4];
    #pragma unroll
    for (int off = 32; off > 0; off >>= 1) s += __shfl_down(s, off);
    if ((t & 63) == 0) red[t >> 6] = s;
    __syncthreads();
    if (t == 0) out_loss[0] = 1.25f * (red[0] + red[1] + red[2] + red[3]) / (float)(N_ROWS * DIM);
}

extern "C" void kernel_launch(void* const* d_in, const int* in_sizes, int n_in,
                              void* d_out, int out_size, void* d_ws, size_t ws_size,
                              hipStream_t stream) {
    const float* x  = (const float*)d_in[0];
    const float* cb = (const float*)d_in[1];
    float* out = (float*)d_out;

    double* c2d = (double*)d_ws;                      // 4096 doubles
    double* nd  = c2d + NCODE;                        // 4096 doubles
    float* cbn = (float*)(nd + NCODE);                // 4096*256 floats
    float* c2  = cbn + (size_t)NCODE * DIM;           // 4096
    float* nx  = c2 + NCODE;                          // 65536
    float* scx = nx + N_ROWS;                         // 65536
    int*   idxv = (int*)(scx + N_ROWS);               // 65536
    float* partials = (float*)(idxv + N_ROWS);        // 65536
    int*   counter  = (int*)(partials + N_ROWS);      // 4 ints
    int*   rowlist  = counter + 4;                    // 65536
    unsigned short* pk = (unsigned short*)(rowlist + N_ROWS);   // 4096*256*2 ushort (packed h+l)

    float* out_q    = out;
    float* out_loss = out + (size_t)N_ROWS * DIM;
    float* out_idxf = out_loss + 1;

    hipLaunchKernelGGL(cb_norm_kernel, dim3(NCODE), dim3(256), 0, stream,
                       cb, cbn, pk, c2, c2d, nd);
    hipLaunchKernelGGL(x_norm_kernel, dim3(N_ROWS / 4), dim3(256), 0, stream, x, nx, scx, counter);
    hipLaunchKernelGGL(argmin_mfma_kernel, dim3(N_ROWS / 128), dim3(256), 0, stream,
                       x, pk, c2, scx, idxv, counter, rowlist);
    hipLaunchKernelGGL(fixup_kernel, dim3(128), dim3(256), 0, stream,
                       x, cb, c2d, nd, counter, rowlist, idxv);
    hipLaunchKernelGGL(gather_loss_kernel, dim3(N_ROWS / 4), dim3(256), 0, stream,
                       x, cbn, c2, nx, idxv, out_q, out_idxf, partials);
    hipLaunchKernelGGL(loss_reduce_kernel, dim3(1), dim3(256), 0, stream,
                       partials, out_loss);
}

// Round 9
// 618.164 us; speedup vs baseline: 4.9370x; 1.4993x over previous
//
#include <hip/hip_runtime.h>
#include <math.h>

#define N_ROWS 65536
#define DIM    256
#define NCODE  4096
#define MARGIN 2e-4f
#define TILE_C 32
#define NTILE  (NCODE / TILE_C)   // 128
#define FB     4                  // fixup rows per batch
#define FIXG   512                // fixup grid

typedef __attribute__((ext_vector_type(8)))  short short8v;
typedef __attribute__((ext_vector_type(4)))  float float4v;
typedef __attribute__((ext_vector_type(16))) float f32x16;

__device__ inline unsigned short f2bf(float f) {
    unsigned u = __float_as_uint(f);
    unsigned r = (u + 0x7fffu + ((u >> 16) & 1u)) >> 16;
    return (unsigned short)r;
}
__device__ inline float bf2f(unsigned short h) {
    return __uint_as_float(((unsigned)h) << 16);
}
__device__ inline void gll16(const void* g, void* l) {
    __builtin_amdgcn_global_load_lds(
        (const __attribute__((address_space(1))) unsigned int*)g,
        (__attribute__((address_space(3))) unsigned int*)l, 16, 0, 0);
}

// ---------------- codebook normalize: cbn fp32, PACKED bf16 split chunks (pk), c2/c2d/ndi
// pk chunk layout: [cb32][ks][hl] -> 1KB chunk; within chunk lane=(hi*32+klo), 8 elems.
__global__ void cb_norm_kernel(const float* __restrict__ cb,
                               float* __restrict__ cbn,
                               unsigned short* __restrict__ pk,
                               float* __restrict__ c2,
                               double* __restrict__ c2d,
                               double* __restrict__ ndi) {
    int k = blockIdx.x;
    int t = threadIdx.x;
    float v = cb[k * DIM + t];
    double dv = (double)v;
    double ss = dv * dv;
    __shared__ double red2[4], red3[4], redn[4];
    #pragma unroll
    for (int off = 32; off > 0; off >>= 1) ss += __shfl_down(ss, off);
    if ((t & 63) == 0) redn[t >> 6] = ss;
    __syncthreads();
    double S = redn[0] + redn[1] + redn[2] + redn[3];
    double nrm = fmax(sqrt(S), 1e-12);
    double cq = dv / nrm;
    float cf = (float)cq;
    cbn[k * DIM + t] = cf;
    unsigned short hb = f2bf(cf);
    unsigned short lb = f2bf(cf - bf2f(hb));
    {
        int cb32 = k >> 5, klo = k & 31, ks = t >> 4, hi = (t >> 3) & 1, j = t & 7;
        size_t ch = ((size_t)cb32 * 16 + ks) * 2;           // h-chunk id
        size_t slot = (size_t)(hi * 32 + klo) * 8 + j;
        pk[(ch + 0) * 512 + slot] = hb;
        pk[(ch + 1) * 512 + slot] = lb;
    }
    double s2 = (double)cf * (double)cf;
    double s3 = cq * cq;
    #pragma unroll
    for (int off = 32; off > 0; off >>= 1) {
        s2 += __shfl_down(s2, off);
        s3 += __shfl_down(s3, off);
    }
    if ((t & 63) == 0) { red2[t >> 6] = s2; red3[t >> 6] = s3; }
    __syncthreads();
    if (t == 0) {
        c2[k]  = (float)(red2[0] + red2[1] + red2[2] + red2[3]);
        c2d[k] = red3[0] + red3[1] + red3[2] + red3[3];
        ndi[k] = 1.0 / nrm;
    }
}

// ---------------- per-row x norms in f64; also zero the fixup counter
__global__ void x_norm_kernel(const float* __restrict__ x,
                              float* __restrict__ nx,
                              float* __restrict__ scx,
                              int* __restrict__ counter) {
    if (blockIdx.x == 0 && threadIdx.x == 0) counter[0] = 0;
    int w = threadIdx.x >> 6;
    int lane = threadIdx.x & 63;
    int row = blockIdx.x * 4 + w;
    float4 v = ((const float4*)(x + (size_t)row * DIM))[lane];
    double ss = (double)v.x * v.x + (double)v.y * v.y
              + (double)v.z * v.z + (double)v.w * v.w;
    #pragma unroll
    for (int off = 32; off > 0; off >>= 1) ss += __shfl_down(ss, off);
    if (lane == 0) {
        double n = fmax(sqrt(ss), 1e-12);
        nx[row]  = (float)n;
        scx[row] = (float)(2.0 / n);
    }
}

// ---------------- main: 32x32x16 split-bf16 MFMA, global_load_lds staging,
// linear conflict-free LDS, 1 barrier/tile. Wave = 32 rows; block = 128 rows.
__attribute__((amdgpu_waves_per_eu(2, 2)))
__global__ void __launch_bounds__(256)
argmin_mfma_kernel(const float* __restrict__ x,
                   const unsigned short* __restrict__ pk,
                   const float* __restrict__ c2,
                   const float* __restrict__ scx,
                   int* __restrict__ idx_out,
                   int* __restrict__ counter,
                   int* __restrict__ rowlist) {
    __shared__ unsigned short buf[2][16384];   // 2 x 32KB

    int tid  = threadIdx.x;
    int lane = tid & 63;
    int wave = tid >> 6;
    int cl31 = lane & 31;
    int hi   = lane >> 5;
    int xbase = blockIdx.x * 128 + wave * 32;

    // ---- load + split X fragments: B-frag row = lane&31, k = hi*8+j
    short8v bh[16], bl[16];
    const float* xr = x + (size_t)(xbase + cl31) * DIM + hi * 8;
    #pragma unroll
    for (int ks = 0; ks < 16; ks++) {
        float4 f0 = *(const float4*)(xr + ks * 16);
        float4 f1 = *(const float4*)(xr + ks * 16 + 4);
        float e[8] = {f0.x, f0.y, f0.z, f0.w, f1.x, f1.y, f1.z, f1.w};
        short8v h, l;
        #pragma unroll
        for (int j = 0; j < 8; j++) {
            unsigned short hb = f2bf(e[j]);
            h[j] = (short)hb;
            l[j] = (short)f2bf(e[j] - bf2f(hb));
        }
        bh[ks] = h;
        bl[ks] = l;
    }
    float scr = scx[xbase + cl31];

    float s1 = 3.4e38f, s2 = 3.4e38f;
    int   i1 = 0x7fffffff;

    // ---- stage tile 0 (each wave: 8 chunks, linear 1KB each)
    {
        const unsigned short* src = pk + ((size_t)wave * 8) * 512 + lane * 8;
        unsigned short* dst = &buf[0][(wave * 8) * 512];
        #pragma unroll
        for (int i = 0; i < 8; i++) gll16(src + i * 512, dst + i * 512);
    }
    __syncthreads();

    int cur = 0;
    for (int t = 0; t < NTILE; t++) {
        int cbb = t * TILE_C;

        // ---- issue next tile's async stages into the other buffer
        if (t + 1 < NTILE) {
            const unsigned short* src =
                pk + ((size_t)(t + 1) * 32 + wave * 8) * 512 + lane * 8;
            unsigned short* dst = &buf[cur ^ 1][(wave * 8) * 512];
            #pragma unroll
            for (int i = 0; i < 8; i++) gll16(src + i * 512, dst + i * 512);
        }

        // ---- 48 MFMA from LDS (A: code row = lane&31, k = hi*8+j -> linear reads)
        const unsigned short* cbuf = &buf[cur][0];
        f32x16 acc = {0.f,0.f,0.f,0.f,0.f,0.f,0.f,0.f,0.f,0.f,0.f,0.f,0.f,0.f,0.f,0.f};
        #pragma unroll
        for (int ks = 0; ks < 16; ks++) {
            short8v ah = *(const short8v*)(cbuf + (size_t)(ks * 2 + 0) * 512 + lane * 8);
            short8v al = *(const short8v*)(cbuf + (size_t)(ks * 2 + 1) * 512 + lane * 8);
            acc = __builtin_amdgcn_mfma_f32_32x32x16_bf16(ah, bh[ks], acc, 0, 0, 0);
            acc = __builtin_amdgcn_mfma_f32_32x32x16_bf16(ah, bl[ks], acc, 0, 0, 0);
            acc = __builtin_amdgcn_mfma_f32_32x32x16_bf16(al, bh[ks], acc, 0, 0, 0);
        }

        // ---- epilogue: scores = c2 - scr*dot; exact best2 with wave-skip
        const float4v* c2p = (const float4v*)(c2 + cbb + hi * 4);
        float4v gq0 = c2p[0], gq1 = c2p[2], gq2 = c2p[4], gq3 = c2p[6];
        float sv[16];
        float mn = 3.4e38f;
        #pragma unroll
        for (int g = 0; g < 4; g++) {
            float4v gg = (g == 0) ? gq0 : (g == 1) ? gq1 : (g == 2) ? gq2 : gq3;
            #pragma unroll
            for (int q = 0; q < 4; q++) {
                float s = gg[q] - scr * acc[g * 4 + q];
                sv[g * 4 + q] = s;
                mn = fminf(mn, s);
            }
        }
        if (!__all(mn >= s2)) {
            #pragma unroll
            for (int g = 0; g < 4; g++) {
                #pragma unroll
                for (int q = 0; q < 4; q++) {
                    float s = sv[g * 4 + q];
                    int ci = cbb + q + 8 * g + 4 * hi;   // ascending in (g,q)
                    if (s < s1) { s2 = s1; s1 = s; i1 = ci; }
                    else if (s < s2) s2 = s;
                }
            }
        }

        __syncthreads();   // drains gll vmcnt per-wave; all waves done with cur
        cur ^= 1;
    }

    // ---- merge the two lane-halves (same row, disjoint codes)
    {
        float o1 = __shfl_xor(s1, 32);
        int   oi = __shfl_xor(i1, 32);
        float o2 = __shfl_xor(s2, 32);
        if (o1 < s1 || (o1 == s1 && oi < i1)) { s2 = fminf(s1, o2); s1 = o1; i1 = oi; }
        else                                   { s2 = fminf(o1, s2); }
    }
    if (lane < 32) {
        int row = xbase + lane;
        idx_out[row] = i1;
        if (s2 - s1 < MARGIN) { int slot = atomicAdd(counter, 1); rowlist[slot] = row; }
    }
}

// ---------------- f64 exact rescore, batched: FB rows share one codebook stream.
// Block stages FB x-rows in LDS (broadcast reads = conflict-free), each thread
// scans 16 codes with FB independent accumulator chains (ILP).
__global__ void fixup_kernel(const float* __restrict__ x,
                             const float* __restrict__ cb,
                             const double* __restrict__ c2d,
                             const double* __restrict__ ndi,
                             const int* __restrict__ counter,
                             const int* __restrict__ rowlist,
                             int* __restrict__ idxv) {
    __shared__ double xs[FB][DIM];        // 8KB
    __shared__ double isx_sh[FB];
    __shared__ double red_bs[4][FB];
    __shared__ int    red_bi[4][FB];
    int t = threadIdx.x, lane = t & 63, wave = t >> 6;
    int cnt = counter[0];

    for (int base = blockIdx.x * FB; base < cnt; base += FIXG * FB) {
        int nb = cnt - base; if (nb > FB) nb = FB;

        // stage x rows
        #pragma unroll
        for (int r = 0; r < FB; r++) {
            if (r < nb) {
                int row = rowlist[base + r];
                xs[r][t] = (double)x[(size_t)row * DIM + t];
            }
        }
        __syncthreads();
        // per-row f64 norm: wave w handles row w
        if (wave < nb) {
            double a0 = xs[wave][lane],       a1 = xs[wave][lane + 64];
            double a2 = xs[wave][lane + 128], a3 = xs[wave][lane + 192];
            double ss = a0 * a0 + a1 * a1 + a2 * a2 + a3 * a3;
            #pragma unroll
            for (int off = 32; off > 0; off >>= 1) ss += __shfl_down(ss, off);
            if (lane == 0) isx_sh[wave] = 2.0 / fmax(sqrt(ss), 1e-12);
        }
        __syncthreads();

        double isx0 = isx_sh[0], isx1 = isx_sh[1], isx2 = isx_sh[2], isx3 = isx_sh[3];
        double bs0 = 1e300, bs1 = 1e300, bs2 = 1e300, bs3 = 1e300;
        int    bi0 = 0x7fffffff, bi1 = 0x7fffffff, bi2 = 0x7fffffff, bi3 = 0x7fffffff;

        for (int k0 = 0; k0 < NCODE / 256; k0++) {
            int k = k0 * 256 + t;
            const float4* cr = (const float4*)(cb + (size_t)k * DIM);
            double d0 = 0.0, d1 = 0.0, d2 = 0.0, d3 = 0.0;
            #pragma unroll 8
            for (int d4 = 0; d4 < DIM / 4; d4++) {
                float4 c = cr[d4];
                double cx = c.x, cy = c.y, cz = c.z, cw = c.w;
                int d = d4 * 4;
                d0 = fma(cx, xs[0][d], d0); d0 = fma(cy, xs[0][d+1], d0);
                d0 = fma(cz, xs[0][d+2], d0); d0 = fma(cw, xs[0][d+3], d0);
                d1 = fma(cx, xs[1][d], d1); d1 = fma(cy, xs[1][d+1], d1);
                d1 = fma(cz, xs[1][d+2], d1); d1 = fma(cw, xs[1][d+3], d1);
                d2 = fma(cx, xs[2][d], d2); d2 = fma(cy, xs[2][d+1], d2);
                d2 = fma(cz, xs[2][d+2], d2); d2 = fma(cw, xs[2][d+3], d2);
                d3 = fma(cx, xs[3][d], d3); d3 = fma(cy, xs[3][d+1], d3);
                d3 = fma(cz, xs[3][d+2], d3); d3 = fma(cw, xs[3][d+3], d3);
            }
            double ndik = ndi[k], c2k = c2d[k];
            double s0 = c2k - isx0 * d0 * ndik;
            double s1v = c2k - isx1 * d1 * ndik;
            double s2v = c2k - isx2 * d2 * ndik;
            double s3v = c2k - isx3 * d3 * ndik;
            if (s0 < bs0 || (s0 == bs0 && k < bi0)) { bs0 = s0; bi0 = k; }
            if (s1v < bs1 || (s1v == bs1 && k < bi1)) { bs1 = s1v; bi1 = k; }
            if (s2v < bs2 || (s2v == bs2 && k < bi2)) { bs2 = s2v; bi2 = k; }
            if (s3v < bs3 || (s3v == bs3 && k < bi3)) { bs3 = s3v; bi3 = k; }
        }

        // wave-level merge per row
        #pragma unroll
        for (int m = 1; m < 64; m <<= 1) {
            double os; int oi;
            os = __shfl_xor(bs0, m); oi = __shfl_xor(bi0, m);
            if (os < bs0 || (os == bs0 && oi < bi0)) { bs0 = os; bi0 = oi; }
            os = __shfl_xor(bs1, m); oi = __shfl_xor(bi1, m);
            if (os < bs1 || (os == bs1 && oi < bi1)) { bs1 = os; bi1 = oi; }
            os = __shfl_xor(bs2, m); oi = __shfl_xor(bi2, m);
            if (os < bs2 || (os == bs2 && oi < bi2)) { bs2 = os; bi2 = oi; }
            os = __shfl_xor(bs3, m); oi = __shfl_xor(bi3, m);
            if (os < bs3 || (os == bs3 && oi < bi3)) { bs3 = os; bi3 = oi; }
        }
        if (lane == 0) {
            red_bs[wave][0] = bs0; red_bi[wave][0] = bi0;
            red_bs[wave][1] = bs1; red_bi[wave][1] = bi1;
            red_bs[wave][2] = bs2; red_bi[wave][2] = bi2;
            red_bs[wave][3] = bs3; red_bi[wave][3] = bi3;
        }
        __syncthreads();
        if (t < nb) {
            double b = red_bs[0][t]; int idx = red_bi[0][t];
            #pragma unroll
            for (int w = 1; w < 4; w++) {
                double ob = red_bs[w][t]; int oi = red_bi[w][t];
                if (ob < b || (ob == b && oi < idx)) { b = ob; idx = oi; }
            }
            idxv[rowlist[base + t]] = idx;
        }
        __syncthreads();
    }
}

// ---------------- gather + per-row loss partial (4 rows/block, float4)
__global__ void gather_loss_kernel(const float* __restrict__ x,
                                   const float* __restrict__ cbn,
                                   const float* __restrict__ c2,
                                   const float* __restrict__ nx,
                                   const int* __restrict__ idxv,
                                   float* __restrict__ out_q,
                                   float* __restrict__ out_idxf,
                                   float* __restrict__ partials) {
    int w = threadIdx.x >> 6, lane = threadIdx.x & 63;
    int row = blockIdx.x * 4 + w;
    int iv = idxv[row];
    float inv_qn = 1.0f / fmaxf(sqrtf(c2[iv]), 1e-12f);
    float inx = 1.0f / nx[row];
    float4 q4 = ((const float4*)(cbn + (size_t)iv * DIM))[lane];
    float4 x4 = ((const float4*)(x + (size_t)row * DIM))[lane];
    float4 qq;
    qq.x = q4.x * inv_qn; qq.y = q4.y * inv_qn;
    qq.z = q4.z * inv_qn; qq.w = q4.w * inv_qn;
    ((float4*)(out_q + (size_t)row * DIM))[lane] = qq;
    float dx = qq.x - x4.x * inx;
    float dy = qq.y - x4.y * inx;
    float dz = qq.z - x4.z * inx;
    float dw = qq.w - x4.w * inx;
    float ss = dx * dx + dy * dy + dz * dz + dw * dw;
    #pragma unroll
    for (int off = 32; off > 0; off >>= 1) ss += __shfl_down(ss, off);
    if (lane == 0) {
        partials[row] = ss;
        out_idxf[row] = (float)iv;
    }
}

// ---------------- final deterministic loss reduction
__global__ void loss_reduce_kernel(const float* __restrict__ partials,
                                   float* __restrict__ out_loss) {
    int t = threadIdx.x;
    float s = 0.0f;
    for (int i = t; i < N_ROWS; i += 256) s += partials[i];
    __shared__ float red[4];
    #pragma unroll
    for (int off = 32; off > 0; off >>= 1) s += __shfl_down(s, off);
    if ((t & 63) == 0) red[t >> 6] = s;
    __syncthreads();
    if (t == 0) out_loss[0] = 1.25f * (red[0] + red[1] + red[2] + red[3]) / (float)(N_ROWS * DIM);
}

extern "C" void kernel_launch(void* const* d_in, const int* in_sizes, int n_in,
                              void* d_out, int out_size, void* d_ws, size_t ws_size,
                              hipStream_t stream) {
    const float* x  = (const float*)d_in[0];
    const float* cb = (const float*)d_in[1];
    float* out = (float*)d_out;

    double* c2d = (double*)d_ws;                      // 4096 doubles
    double* ndi = c2d + NCODE;                        // 4096 doubles (1/norm)
    float* cbn = (float*)(ndi + NCODE);               // 4096*256 floats
    float* c2  = cbn + (size_t)NCODE * DIM;           // 4096
    float* nx  = c2 + NCODE;                          // 65536
    float* scx = nx + N_ROWS;                         // 65536
    int*   idxv = (int*)(scx + N_ROWS);               // 65536
    float* partials = (float*)(idxv + N_ROWS);        // 65536
    int*   counter  = (int*)(partials + N_ROWS);      // 4 ints
    int*   rowlist  = counter + 4;                    // 65536
    unsigned short* pk = (unsigned short*)(rowlist + N_ROWS);   // 4096*256*2 ushort (packed h+l)

    float* out_q    = out;
    float* out_loss = out + (size_t)N_ROWS * DIM;
    float* out_idxf = out_loss + 1;

    hipLaunchKernelGGL(cb_norm_kernel, dim3(NCODE), dim3(256), 0, stream,
                       cb, cbn, pk, c2, c2d, ndi);
    hipLaunchKernelGGL(x_norm_kernel, dim3(N_ROWS / 4), dim3(256), 0, stream, x, nx, scx, counter);
    hipLaunchKernelGGL(argmin_mfma_kernel, dim3(N_ROWS / 128), dim3(256), 0, stream,
                       x, pk, c2, scx, idxv, counter, rowlist);
    hipLaunchKernelGGL(fixup_kernel, dim3(FIXG), dim3(256), 0, stream,
                       x, cb, c2d, ndi, counter, rowlist, idxv);
    hipLaunchKernelGGL(gather_loss_kernel, dim3(N_ROWS / 4), dim3(256), 0, stream,
                       x, cbn, c2, nx, idxv, out_q, out_idxf, partials);
    hipLaunchKernelGGL(loss_reduce_kernel, dim3(1), dim3(256), 0, stream,
                       partials, out_loss);
}

// Round 13
// 599.277 us; speedup vs baseline: 5.0926x; 1.0315x over previous
//
#include <hip/hip_runtime.h>
#include <math.h>

#define N_ROWS 65536
#define DIM    256
#define NCODE  4096
#define MARGIN 2e-4f
#define TILE_C 32
#define NTILE  (NCODE / TILE_C)   // 128
#define FB     8                  // fixup rows per batch
#define KCH    1024               // fixup codes per chunk
#define NCH    (NCODE / KCH)      // 4
#define FIXG   512

typedef __attribute__((ext_vector_type(8)))  short short8v;
typedef __attribute__((ext_vector_type(4)))  float float4v;
typedef __attribute__((ext_vector_type(16))) float f32x16;

__device__ inline unsigned short f2bf(float f) {
    unsigned u = __float_as_uint(f);
    unsigned r = (u + 0x7fffu + ((u >> 16) & 1u)) >> 16;
    return (unsigned short)r;
}
__device__ inline float bf2f(unsigned short h) {
    return __uint_as_float(((unsigned)h) << 16);
}
__device__ inline void gll16(const void* g, void* l) {
    __builtin_amdgcn_global_load_lds(
        (const __attribute__((address_space(1))) unsigned int*)g,
        (__attribute__((address_space(3))) unsigned int*)l, 16, 0, 0);
}

// ---------------- codebook normalize: PACKED bf16 split chunks (pk), c2 (fp32), c2d/ndi (f64)
// pk chunk = (cb32*16 + ks)*2 + hl (1KB each); slot = lane*8 + j, lane = hi*32+klo (A-frag order)
__global__ void cb_norm_kernel(const float* __restrict__ cb,
                               unsigned short* __restrict__ pk,
                               float* __restrict__ c2,
                               double* __restrict__ c2d,
                               double* __restrict__ ndi) {
    int k = blockIdx.x;
    int t = threadIdx.x;
    float v = cb[k * DIM + t];
    double dv = (double)v;
    double ss = dv * dv;
    __shared__ double red2[4], red3[4], redn[4];
    #pragma unroll
    for (int off = 32; off > 0; off >>= 1) ss += __shfl_down(ss, off);
    if ((t & 63) == 0) redn[t >> 6] = ss;
    __syncthreads();
    double S = redn[0] + redn[1] + redn[2] + redn[3];
    double nrm = fmax(sqrt(S), 1e-12);
    double cq = dv / nrm;
    float cf = (float)cq;
    unsigned short hb = f2bf(cf);
    unsigned short lb = f2bf(cf - bf2f(hb));
    {
        int cb32 = k >> 5, klo = k & 31, ks = t >> 4, hi = (t >> 3) & 1, j = t & 7;
        size_t ch = ((size_t)cb32 * 16 + ks) * 2;
        size_t slot = (size_t)(hi * 32 + klo) * 8 + j;
        pk[(ch + 0) * 512 + slot] = hb;
        pk[(ch + 1) * 512 + slot] = lb;
    }
    double s2 = (double)cf * (double)cf;
    double s3 = cq * cq;
    #pragma unroll
    for (int off = 32; off > 0; off >>= 1) {
        s2 += __shfl_down(s2, off);
        s3 += __shfl_down(s3, off);
    }
    if ((t & 63) == 0) { red2[t >> 6] = s2; red3[t >> 6] = s3; }
    __syncthreads();
    if (t == 0) {
        c2[k]  = (float)(red2[0] + red2[1] + red2[2] + red2[3]);
        c2d[k] = red3[0] + red3[1] + red3[2] + red3[3];
        ndi[k] = 1.0 / nrm;
    }
}

// ---------------- per-row x norms in f64; zero the fixup counter
__global__ void x_norm_kernel(const float* __restrict__ x,
                              float* __restrict__ nx,
                              float* __restrict__ scx,
                              int* __restrict__ counter) {
    if (blockIdx.x == 0 && threadIdx.x == 0) counter[0] = 0;
    int w = threadIdx.x >> 6;
    int lane = threadIdx.x & 63;
    int row = blockIdx.x * 4 + w;
    float4 v = ((const float4*)(x + (size_t)row * DIM))[lane];
    double ss = (double)v.x * v.x + (double)v.y * v.y
              + (double)v.z * v.z + (double)v.w * v.w;
    #pragma unroll
    for (int off = 32; off > 0; off >>= 1) ss += __shfl_down(ss, off);
    if (lane == 0) {
        double n = fmax(sqrt(ss), 1e-12);
        nx[row]  = (float)n;
        scx[row] = (float)(2.0 / n);
    }
}

// ---------------- main: 3-pass split-bf16 32x32x16 MFMA + EXACT top-2 + gap flag.
// (byte-identical logic to the twice-proven R8 kernel)
__attribute__((amdgpu_waves_per_eu(2, 2)))
__global__ void __launch_bounds__(256)
argmin_mfma_kernel(const float* __restrict__ x,
                   const unsigned short* __restrict__ pk,
                   const float* __restrict__ c2,
                   const float* __restrict__ scx,
                   int* __restrict__ idx_out,
                   int* __restrict__ counter,
                   int* __restrict__ rowlist) {
    __shared__ unsigned short buf[2][16384];   // 2 x 32KB

    int tid  = threadIdx.x;
    int lane = tid & 63;
    int wave = tid >> 6;
    int cl31 = lane & 31;
    int hi   = lane >> 5;
    int xbase = blockIdx.x * 128 + wave * 32;

    // ---- load + split X fragments: B-frag row = lane&31, k = hi*8+j
    short8v bh[16], bl[16];
    const float* xr = x + (size_t)(xbase + cl31) * DIM + hi * 8;
    #pragma unroll
    for (int ks = 0; ks < 16; ks++) {
        float4 f0 = *(const float4*)(xr + ks * 16);
        float4 f1 = *(const float4*)(xr + ks * 16 + 4);
        float e[8] = {f0.x, f0.y, f0.z, f0.w, f1.x, f1.y, f1.z, f1.w};
        short8v h, l;
        #pragma unroll
        for (int j = 0; j < 8; j++) {
            unsigned short hb = f2bf(e[j]);
            h[j] = (short)hb;
            l[j] = (short)f2bf(e[j] - bf2f(hb));
        }
        bh[ks] = h;
        bl[ks] = l;
    }
    float scr = scx[xbase + cl31];

    float s1 = 3.4e38f, s2 = 3.4e38f;
    int   i1 = 0x7fffffff;

    // ---- stage tile 0 (each wave: 8 chunks, linear 1KB each)
    {
        const unsigned short* src = pk + ((size_t)wave * 8) * 512 + lane * 8;
        unsigned short* dst = &buf[0][(wave * 8) * 512];
        #pragma unroll
        for (int i = 0; i < 8; i++) gll16(src + i * 512, dst + i * 512);
    }
    __syncthreads();

    int cur = 0;
    for (int t = 0; t < NTILE; t++) {
        int cbb = t * TILE_C;

        if (t + 1 < NTILE) {
            const unsigned short* src =
                pk + ((size_t)(t + 1) * 32 + wave * 8) * 512 + lane * 8;
            unsigned short* dst = &buf[cur ^ 1][(wave * 8) * 512];
            #pragma unroll
            for (int i = 0; i < 8; i++) gll16(src + i * 512, dst + i * 512);
        }

        // ---- 48 MFMA from LDS (A: code = lane&31, k = hi*8+j; linear reads)
        const unsigned short* cbuf = &buf[cur][0];
        f32x16 acc = {0.f,0.f,0.f,0.f,0.f,0.f,0.f,0.f,0.f,0.f,0.f,0.f,0.f,0.f,0.f,0.f};
        #pragma unroll
        for (int ks = 0; ks < 16; ks++) {
            short8v ah = *(const short8v*)(cbuf + (size_t)(ks * 2 + 0) * 512 + lane * 8);
            short8v al = *(const short8v*)(cbuf + (size_t)(ks * 2 + 1) * 512 + lane * 8);
            acc = __builtin_amdgcn_mfma_f32_32x32x16_bf16(ah, bh[ks], acc, 0, 0, 0);
            acc = __builtin_amdgcn_mfma_f32_32x32x16_bf16(ah, bl[ks], acc, 0, 0, 0);
            acc = __builtin_amdgcn_mfma_f32_32x32x16_bf16(al, bh[ks], acc, 0, 0, 0);
        }

        // ---- epilogue: scores = c2 - scr*dot; exact best2 with wave-skip
        const float4v* c2p = (const float4v*)(c2 + cbb + hi * 4);
        float4v gq0 = c2p[0], gq1 = c2p[2], gq2 = c2p[4], gq3 = c2p[6];
        float sv[16];
        float mn = 3.4e38f;
        #pragma unroll
        for (int g = 0; g < 4; g++) {
            float4v gg = (g == 0) ? gq0 : (g == 1) ? gq1 : (g == 2) ? gq2 : gq3;
            #pragma unroll
            for (int q = 0; q < 4; q++) {
                float s = gg[q] - scr * acc[g * 4 + q];
                sv[g * 4 + q] = s;
                mn = fminf(mn, s);
            }
        }
        if (!__all(mn >= s2)) {
            #pragma unroll
            for (int g = 0; g < 4; g++) {
                #pragma unroll
                for (int q = 0; q < 4; q++) {
                    float s = sv[g * 4 + q];
                    int ci = cbb + q + 8 * g + 4 * hi;   // ascending per thread
                    if (s < s1) { s2 = s1; s1 = s; i1 = ci; }
                    else if (s < s2) s2 = s;
                }
            }
        }

        __syncthreads();
        cur ^= 1;
    }

    // ---- merge the two lane-halves (same row, disjoint codes): exact global top-2
    {
        float o1 = __shfl_xor(s1, 32);
        int   oi = __shfl_xor(i1, 32);
        float o2 = __shfl_xor(s2, 32);
        if (o1 < s1 || (o1 == s1 && oi < i1)) { s2 = fminf(s1, o2); s1 = o1; i1 = oi; }
        else                                   { s2 = fminf(o1, s2); }
    }
    if (lane < 32) {
        int row = xbase + lane;
        idx_out[row] = i1;
        if (s2 - s1 < MARGIN) { int slot = atomicAdd(counter, 1); rowlist[slot] = row; }
    }
}

// ---------------- fixup 2D: (8-row batch) x (1024-code chunk) exact f64 partial argmin
__global__ void fixup2d_kernel(const float* __restrict__ x,
                               const float* __restrict__ cb,
                               const double* __restrict__ c2d,
                               const double* __restrict__ ndi,
                               const int* __restrict__ counter,
                               const int* __restrict__ rowlist,
                               double* __restrict__ pb_s,
                               int* __restrict__ pb_i) {
    __shared__ double xs[FB][DIM];        // 16KB
    __shared__ double isx_sh[FB];
    __shared__ double red_s[4][FB];
    __shared__ int    red_i[4][FB];
    int t = threadIdx.x, lane = t & 63, wave = t >> 6;
    int cnt = counter[0];
    int nbat = (cnt + FB - 1) / FB;
    int nwork = nbat * NCH;

    for (int w = blockIdx.x; w < nwork; w += FIXG) {
        int batch = w / NCH, chunk = w - batch * NCH;
        int base = batch * FB;
        int nb = cnt - base; if (nb > FB) nb = FB;

        #pragma unroll
        for (int r = 0; r < FB; r++)
            if (r < nb) xs[r][t] = (double)x[(size_t)rowlist[base + r] * DIM + t];
        __syncthreads();

        for (int rr = wave; rr < nb; rr += 4) {
            double a0 = xs[rr][lane],       a1 = xs[rr][lane + 64];
            double a2 = xs[rr][lane + 128], a3 = xs[rr][lane + 192];
            double ss = a0 * a0 + a1 * a1 + a2 * a2 + a3 * a3;
            #pragma unroll
            for (int m = 1; m < 64; m <<= 1) ss += __shfl_xor(ss, m);
            if (lane == 0) isx_sh[rr] = 2.0 / fmax(sqrt(ss), 1e-12);
        }
        __syncthreads();

        double bs[FB]; int bi[FB];
        #pragma unroll
        for (int r = 0; r < FB; r++) { bs[r] = 1e300; bi[r] = 0x7fffffff; }

        for (int k0 = 0; k0 < KCH / 256; k0++) {
            int k = chunk * KCH + k0 * 256 + t;
            const float4* cr = (const float4*)(cb + (size_t)k * DIM);
            double d[FB];
            #pragma unroll
            for (int r = 0; r < FB; r++) d[r] = 0.0;
            #pragma unroll 4
            for (int d4 = 0; d4 < DIM / 4; d4++) {
                float4 c = cr[d4];
                double cx = c.x, cy = c.y, cz = c.z, cw = c.w;
                int dd = d4 * 4;
                #pragma unroll
                for (int r = 0; r < FB; r++) {
                    d[r] = fma(cx, xs[r][dd],     d[r]);
                    d[r] = fma(cy, xs[r][dd + 1], d[r]);
                    d[r] = fma(cz, xs[r][dd + 2], d[r]);
                    d[r] = fma(cw, xs[r][dd + 3], d[r]);
                }
            }
            double ndik = ndi[k], c2k = c2d[k];
            #pragma unroll
            for (int r = 0; r < FB; r++) {
                double sc = c2k - isx_sh[r] * d[r] * ndik;
                if (sc < bs[r] || (sc == bs[r] && k < bi[r])) { bs[r] = sc; bi[r] = k; }
            }
        }

        #pragma unroll
        for (int r = 0; r < FB; r++) {
            double b = bs[r]; int idx = bi[r];
            #pragma unroll
            for (int m = 1; m < 64; m <<= 1) {
                double ob = __shfl_xor(b, m);
                int   oi = __shfl_xor(idx, m);
                if (ob < b || (ob == b && oi < idx)) { b = ob; idx = oi; }
            }
            if (lane == 0) { red_s[wave][r] = b; red_i[wave][r] = idx; }
        }
        __syncthreads();
        if (t < nb) {
            double b = red_s[0][t]; int idx = red_i[0][t];
            #pragma unroll
            for (int ww = 1; ww < 4; ww++) {
                double ob = red_s[ww][t]; int oi = red_i[ww][t];
                if (ob < b || (ob == b && oi < idx)) { b = ob; idx = oi; }
            }
            pb_s[(size_t)(base + t) * NCH + chunk] = b;
            pb_i[(size_t)(base + t) * NCH + chunk] = idx;
        }
        __syncthreads();
    }
}

// ---------------- merge chunk partials -> final exact idx for flagged rows
__global__ void fixmerge_kernel(const int* __restrict__ counter,
                                const int* __restrict__ rowlist,
                                const double* __restrict__ pb_s,
                                const int* __restrict__ pb_i,
                                int* __restrict__ idxv) {
    int cnt = counter[0];
    for (int s = blockIdx.x * 256 + threadIdx.x; s < cnt; s += gridDim.x * 256) {
        double b = pb_s[(size_t)s * NCH]; int idx = pb_i[(size_t)s * NCH];
        #pragma unroll
        for (int c = 1; c < NCH; c++) {
            double ob = pb_s[(size_t)s * NCH + c]; int oi = pb_i[(size_t)s * NCH + c];
            if (ob < b || (ob == b && oi < idx)) { b = ob; idx = oi; }
        }
        idxv[rowlist[s]] = idx;
    }
}

// ---------------- gather + per-row loss partial (4 rows/block, float4; cb * 1/||cb||)
__global__ void gather_loss_kernel(const float* __restrict__ x,
                                   const float* __restrict__ cb,
                                   const double* __restrict__ ndi,
                                   const float* __restrict__ nx,
                                   const int* __restrict__ idxv,
                                   float* __restrict__ out_q,
                                   float* __restrict__ out_idxf,
                                   float* __restrict__ partials) {
    int w = threadIdx.x >> 6, lane = threadIdx.x & 63;
    int row = blockIdx.x * 4 + w;
    int iv = idxv[row];
    float ndif = (float)ndi[iv];
    float inx = 1.0f / nx[row];
    float4 q4 = ((const float4*)(cb + (size_t)iv * DIM))[lane];
    float4 x4 = ((const float4*)(x + (size_t)row * DIM))[lane];
    float4 qq;
    qq.x = q4.x * ndif; qq.y = q4.y * ndif;
    qq.z = q4.z * ndif; qq.w = q4.w * ndif;
    ((float4*)(out_q + (size_t)row * DIM))[lane] = qq;
    float dx = qq.x - x4.x * inx;
    float dy = qq.y - x4.y * inx;
    float dz = qq.z - x4.z * inx;
    float dw = qq.w - x4.w * inx;
    float ss = dx * dx + dy * dy + dz * dz + dw * dw;
    #pragma unroll
    for (int off = 32; off > 0; off >>= 1) ss += __shfl_down(ss, off);
    if (lane == 0) {
        partials[row] = ss;
        out_idxf[row] = (float)iv;
    }
}

// ---------------- final deterministic loss reduction
__global__ void loss_reduce_kernel(const float* __restrict__ partials,
                                   float* __restrict__ out_loss) {
    int t = threadIdx.x;
    float s = 0.0f;
    for (int i = t; i < N_ROWS; i += 256) s += partials[i];
    __shared__ float red[4];
    #pragma unroll
    for (int off = 32; off > 0; off >>= 1) s += __shfl_down(s, off);
    if ((t & 63) == 0) red[t >> 6] = s;
    __syncthreads();
    if (t == 0) out_loss[0] = 1.25f * (red[0] + red[1] + red[2] + red[3]) / (float)(N_ROWS * DIM);
}

extern "C" void kernel_launch(void* const* d_in, const int* in_sizes, int n_in,
                              void* d_out, int out_size, void* d_ws, size_t ws_size,
                              hipStream_t stream) {
    const float* x  = (const float*)d_in[0];
    const float* cb = (const float*)d_in[1];
    float* out = (float*)d_out;

    // doubles first (alignment), then f32/i32, then pk.  Total ~= 8.5 MB.
    double* c2d  = (double*)d_ws;                       // 4096 dbl
    double* ndi  = c2d + NCODE;                         // 4096 dbl
    double* pb_s = ndi + NCODE;                         // 65536*4 dbl (2MB)
    float*  c2   = (float*)(pb_s + (size_t)N_ROWS * NCH);  // 4096
    float*  nx   = c2 + NCODE;                          // 65536
    float*  scx  = nx + N_ROWS;                         // 65536
    int*    idxv = (int*)(scx + N_ROWS);                // 65536
    float*  partials = (float*)(idxv + N_ROWS);         // 65536
    int*    counter  = (int*)(partials + N_ROWS);       // 8 ints
    int*    rowlist  = counter + 8;                     // 65536
    int*    pb_i     = rowlist + N_ROWS;                // 65536*4 (1MB)
    unsigned short* pk = (unsigned short*)(pb_i + (size_t)N_ROWS * NCH);  // 4MB

    float* out_q    = out;
    float* out_loss = out + (size_t)N_ROWS * DIM;
    float* out_idxf = out_loss + 1;

    hipLaunchKernelGGL(cb_norm_kernel, dim3(NCODE), dim3(256), 0, stream,
                       cb, pk, c2, c2d, ndi);
    hipLaunchKernelGGL(x_norm_kernel, dim3(N_ROWS / 4), dim3(256), 0, stream, x, nx, scx, counter);
    hipLaunchKernelGGL(argmin_mfma_kernel, dim3(N_ROWS / 128), dim3(256), 0, stream,
                       x, pk, c2, scx, idxv, counter, rowlist);
    hipLaunchKernelGGL(fixup2d_kernel, dim3(FIXG), dim3(256), 0, stream,
                       x, cb, c2d, ndi, counter, rowlist, pb_s, pb_i);
    hipLaunchKernelGGL(fixmerge_kernel, dim3(64), dim3(256), 0, stream,
                       counter, rowlist, pb_s, pb_i, idxv);
    hipLaunchKernelGGL(gather_loss_kernel, dim3(N_ROWS / 4), dim3(256), 0, stream,
                       x, cb, ndi, nx, idxv, out_q, out_idxf, partials);
    hipLaunchKernelGGL(loss_reduce_kernel, dim3(1), dim3(256), 0, stream,
                       partials, out_loss);
}